// Round 2
// baseline (1821.042 us; speedup 1.0000x reference)
//
#include <hip/hip_runtime.h>
#include <cstddef>

// Problem constants (static shapes from the reference)
#define LQ   17821
#define BS   2
#define MTOK (BS * LQ)       // 35642 token rows
#define CDIM 256
#define NHD  8
#define DHEAD 32
#define DFFN 1024

// ---------------------------------------------------------------------------
// RMSNorm (+ optional pos-add producing q)
// ---------------------------------------------------------------------------
template <bool ADD_POS>
__global__ __launch_bounds__(256)
void rmsnorm_kernel(const float* __restrict__ x, const float* __restrict__ pos,
                    const float* __restrict__ w,
                    float* __restrict__ outN, float* __restrict__ outQ) {
    const size_t base = (size_t)blockIdx.x * CDIM;
    const int c = threadIdx.x;
    const float v = x[base + c];
    float ss = v * v;
#pragma unroll
    for (int m = 1; m < 64; m <<= 1) ss += __shfl_xor(ss, m, 64);
    __shared__ float red[4];
    if ((threadIdx.x & 63) == 0) red[threadIdx.x >> 6] = ss;
    __syncthreads();
    const float tot = red[0] + red[1] + red[2] + red[3];
    const float r = rsqrtf(tot * (1.0f / CDIM) + 1e-6f);
    const float nv = v * r * w[c];
    outN[base + c] = nv;
    if (ADD_POS) outQ[base + c] = nv + pos[base + c];
}

// ---------------------------------------------------------------------------
// Tiled fp32 GEMM: C[M,N] = A[M,K] * W[N,K]^T (+ epilogues)
// MODE 0: out = acc + bias1                         (plain, row-major M x N)
// MODE 1: value layout write (b, h, q, c)
// MODE 2: out = resid + ls * (acc + bias1)          (LayerScale residual)
// MODE 3: out = silu(acc1 + bias1) * (acc2 + bias2) (SwiGLU, dual weights)
// ---------------------------------------------------------------------------
#define BM 64
#define BN 64
#define BKt 16

template <int MODE>
__global__ __launch_bounds__(256)
void gemm_kernel(const float* __restrict__ A,
                 const float* __restrict__ B1, const float* __restrict__ bias1,
                 const float* __restrict__ B2, const float* __restrict__ bias2,
                 const float* __restrict__ resid, const float* __restrict__ ls,
                 float* __restrict__ out, int M, int N, int K) {
    __shared__ float As[BKt][BM + 4];
    __shared__ float Bs[BKt][BN + 4];
    __shared__ float Bs2[(MODE == 3) ? BKt : 1][BN + 4];

    const int tid = threadIdx.x;
    const int m0 = blockIdx.x * BM;
    const int n0 = blockIdx.y * BN;
    const int lr = tid >> 2;          // 0..63: tile row for loads
    const int lk = (tid & 3) << 2;    // 0/4/8/12: k-offset (float4)
    const int ty = tid >> 4;          // 0..15
    const int tx = tid & 15;          // 0..15

    float acc[4][4] = {};
    float acc2[4][4] = {};

    for (int k0 = 0; k0 < K; k0 += BKt) {
        const int gm = m0 + lr;
        float4 av = make_float4(0.f, 0.f, 0.f, 0.f);
        if (gm < M) av = *(const float4*)&A[(size_t)gm * K + k0 + lk];
        As[lk + 0][lr] = av.x;
        As[lk + 1][lr] = av.y;
        As[lk + 2][lr] = av.z;
        As[lk + 3][lr] = av.w;
        const float4 bv = *(const float4*)&B1[(size_t)(n0 + lr) * K + k0 + lk];
        Bs[lk + 0][lr] = bv.x;
        Bs[lk + 1][lr] = bv.y;
        Bs[lk + 2][lr] = bv.z;
        Bs[lk + 3][lr] = bv.w;
        if constexpr (MODE == 3) {
            const float4 bw = *(const float4*)&B2[(size_t)(n0 + lr) * K + k0 + lk];
            Bs2[lk + 0][lr] = bw.x;
            Bs2[lk + 1][lr] = bw.y;
            Bs2[lk + 2][lr] = bw.z;
            Bs2[lk + 3][lr] = bw.w;
        }
        __syncthreads();
#pragma unroll
        for (int k = 0; k < BKt; ++k) {
            const float4 a = *(const float4*)&As[k][ty * 4];
            const float4 b = *(const float4*)&Bs[k][tx * 4];
            const float am[4] = {a.x, a.y, a.z, a.w};
            const float bn[4] = {b.x, b.y, b.z, b.w};
#pragma unroll
            for (int i = 0; i < 4; ++i)
#pragma unroll
                for (int j = 0; j < 4; ++j)
                    acc[i][j] = fmaf(am[i], bn[j], acc[i][j]);
            if constexpr (MODE == 3) {
                const float4 b2 = *(const float4*)&Bs2[k][tx * 4];
                const float b2n[4] = {b2.x, b2.y, b2.z, b2.w};
#pragma unroll
                for (int i = 0; i < 4; ++i)
#pragma unroll
                    for (int j = 0; j < 4; ++j)
                        acc2[i][j] = fmaf(am[i], b2n[j], acc2[i][j]);
            }
        }
        __syncthreads();
    }

#pragma unroll
    for (int i = 0; i < 4; ++i) {
        const int m = m0 + ty * 4 + i;
        if (m >= M) continue;
#pragma unroll
        for (int j = 0; j < 4; ++j) {
            const int n = n0 + tx * 4 + j;
            const float v = acc[i][j] + bias1[n];
            if constexpr (MODE == 0) {
                out[(size_t)m * N + n] = v;
            } else if constexpr (MODE == 1) {
                const int b = m / LQ;
                const int qi = m - b * LQ;
                const int h = n >> 5;
                const int c = n & 31;
                out[((size_t)(b * NHD + h) * LQ + qi) * DHEAD + c] = v;
            } else if constexpr (MODE == 2) {
                out[(size_t)m * N + n] = resid[(size_t)m * N + n] + ls[n] * v;
            } else {  // MODE 3 SwiGLU
                const float sig = 1.0f / (1.0f + expf(-v));
                const float v2 = acc2[i][j] + bias2[n];
                out[(size_t)m * N + n] = v * sig * v2;
            }
        }
    }
}

// ---------------------------------------------------------------------------
// MSDeformAttn sampling: one block per token; 8 heads x 32 channels.
// value layout: (b, h, Lq, 32).  off: (M, 256).  awl logits: (M, 128).
// ref: (bs, Lq, 4, 2).  out: (M, 256) i.e. (b, q, h, c).
// ---------------------------------------------------------------------------
__global__ __launch_bounds__(256)
void sample_kernel(const float* __restrict__ value,
                   const float* __restrict__ off,
                   const float* __restrict__ awl,
                   const float* __restrict__ ref,
                   float* __restrict__ out) {
    const int row = blockIdx.x;            // 0..M-1
    const int b = row / LQ;
    const int h = threadIdx.x >> 5;
    const int c = threadIdx.x & 31;

    // softmax over the 16 (level, point) logits for this (token, head)
    const float* lg = &awl[(size_t)row * 128 + h * 16];
    float w[16];
    float mx = -3.4e38f;
#pragma unroll
    for (int i = 0; i < 16; ++i) { w[i] = lg[i]; mx = fmaxf(mx, w[i]); }
    float s = 0.f;
#pragma unroll
    for (int i = 0; i < 16; ++i) { w[i] = expf(w[i] - mx); s += w[i]; }
    const float inv = 1.0f / s;

    const float* offp = &off[(size_t)row * 256 + h * 32];
    const int Hs[4] = {100, 50, 25, 13};
    const int Ws[4] = {134, 67, 34, 17};
    const int st[4] = {0, 13400, 16750, 17600};

    float acc = 0.f;
#pragma unroll
    for (int lv = 0; lv < 4; ++lv) {
        const float rx = ref[((size_t)row * 4 + lv) * 2 + 0];
        const float ry = ref[((size_t)row * 4 + lv) * 2 + 1];
        const int H = Hs[lv], W = Ws[lv];
        const float* vb = value + ((size_t)(b * NHD + h) * LQ + st[lv]) * DHEAD + c;
#pragma unroll
        for (int p = 0; p < 4; ++p) {
            const float ox = offp[(lv * 4 + p) * 2 + 0];
            const float oy = offp[(lv * 4 + p) * 2 + 1];
            const float xf = (rx + ox / (float)W) * (float)W - 0.5f;
            const float yf = (ry + oy / (float)H) * (float)H - 0.5f;
            const float x0f = floorf(xf), y0f = floorf(yf);
            const float fx = xf - x0f, fy = yf - y0f;
            const int x0 = (int)x0f, y0 = (int)y0f;
            const float w00 = (1.f - fx) * (1.f - fy);
            const float w01 = fx * (1.f - fy);
            const float w10 = (1.f - fx) * fy;
            const float w11 = fx * fy;
            float v = 0.f;
            if (y0 >= 0 && y0 < H) {
                const float* r0 = vb + (size_t)y0 * W * DHEAD;
                if (x0 >= 0 && x0 < W)         v += w00 * r0[(size_t)x0 * DHEAD];
                if (x0 + 1 >= 0 && x0 + 1 < W) v += w01 * r0[(size_t)(x0 + 1) * DHEAD];
            }
            if (y0 + 1 >= 0 && y0 + 1 < H) {
                const float* r1 = vb + (size_t)(y0 + 1) * W * DHEAD;
                if (x0 >= 0 && x0 < W)         v += w10 * r1[(size_t)x0 * DHEAD];
                if (x0 + 1 >= 0 && x0 + 1 < W) v += w11 * r1[(size_t)(x0 + 1) * DHEAD];
            }
            acc += w[lv * 4 + p] * inv * v;
        }
    }
    out[(size_t)row * 256 + h * 32 + c] = acc;
}

// ---------------------------------------------------------------------------
// Workspace plan (peak 3.5*MC floats = ~122 MiB):
//   R0 = ws[0, MC)      : normed -> off -> x
//   R1 = ws[MC, 2MC)    : q -> sampled -> h-chunk (<= MC)
//   R2 = ws[2MC, 3MC)   : value -> n2
//   R3 = ws[3MC, 3.5MC) : attention-weight logits (M x 128)
// ---------------------------------------------------------------------------
extern "C" void kernel_launch(void* const* d_in, const int* in_sizes, int n_in,
                              void* d_out, int out_size, void* d_ws, size_t ws_size,
                              hipStream_t stream) {
    const float* query      = (const float*)d_in[0];
    const float* query_pos  = (const float*)d_in[1];
    const float* ref        = (const float*)d_in[2];
    // d_in[3]=spatial_shapes, d_in[4]=level_start_index (unused, baked in)
    const float* norm_attn_w = (const float*)d_in[5];
    const float* Wv   = (const float*)d_in[6];
    const float* bv   = (const float*)d_in[7];
    const float* Woff = (const float*)d_in[8];
    const float* boff = (const float*)d_in[9];
    const float* Waw  = (const float*)d_in[10];
    const float* baw  = (const float*)d_in[11];
    const float* Wo   = (const float*)d_in[12];
    const float* bo   = (const float*)d_in[13];
    const float* ls_attn = (const float*)d_in[14];
    const float* norm_ffn_w = (const float*)d_in[15];
    const float* W1 = (const float*)d_in[16];
    const float* b1 = (const float*)d_in[17];
    const float* W2 = (const float*)d_in[18];
    const float* b2 = (const float*)d_in[19];
    const float* W3 = (const float*)d_in[20];
    const float* b3 = (const float*)d_in[21];
    const float* ls_ffn = (const float*)d_in[22];
    float* out = (float*)d_out;

    float* ws = (float*)d_ws;
    const size_t MC = (size_t)MTOK * CDIM;   // 9,124,352 floats
    float* R0 = ws;
    float* R1 = ws + MC;
    float* R2 = ws + 2 * MC;
    float* R3 = ws + 3 * MC;   // M x 128

    const int gx = (MTOK + BM - 1) / BM;  // 557

    // 1. normed -> R0, q = normed + pos -> R1
    rmsnorm_kernel<true><<<MTOK, 256, 0, stream>>>(query, query_pos, norm_attn_w, R0, R1);
    // 2. value = normed @ Wv^T + bv  -> R2, (b,h,q,c) layout.  (R0 dead after)
    gemm_kernel<1><<<dim3(gx, CDIM / BN), 256, 0, stream>>>(
        R0, Wv, bv, nullptr, nullptr, nullptr, nullptr, R2, MTOK, CDIM, CDIM);
    // 3. off = q @ Woff^T + boff -> R0
    gemm_kernel<0><<<dim3(gx, 256 / BN), 256, 0, stream>>>(
        R1, Woff, boff, nullptr, nullptr, nullptr, nullptr, R0, MTOK, 256, CDIM);
    // 4. awl = q @ Waw^T + baw -> R3   (R1/q dead after)
    gemm_kernel<0><<<dim3(gx, 128 / BN), 256, 0, stream>>>(
        R1, Waw, baw, nullptr, nullptr, nullptr, nullptr, R3, MTOK, 128, CDIM);
    // 5. sampled -> R1  (R0/off, R2/value, R3/awl dead after)
    sample_kernel<<<MTOK, 256, 0, stream>>>(R2, R0, R3, ref, R1);
    // 6. x = query + ls_attn * (sampled @ Wo^T + bo) -> R0
    gemm_kernel<2><<<dim3(gx, CDIM / BN), 256, 0, stream>>>(
        R1, Wo, bo, nullptr, nullptr, query, ls_attn, R0, MTOK, CDIM, CDIM);
    // 7. n2 = rmsnorm(x) -> R2
    rmsnorm_kernel<false><<<MTOK, 256, 0, stream>>>(R0, nullptr, norm_ffn_w, R2, nullptr);
    // 8/9. FFN chunked over M so the hidden activation fits in R1 (<= MC).
    const int MCHUNK = 8896;  // 139 * 64; 8896*1024 = 9,109,504 <= MC
    for (int ms = 0; ms < MTOK; ms += MCHUNK) {
        const int mc = (MTOK - ms < MCHUNK) ? (MTOK - ms) : MCHUNK;
        const int gxc = (mc + BM - 1) / BM;
        // h = silu(n2 @ W1^T + b1) * (n2 @ W2^T + b2) -> R1
        gemm_kernel<3><<<dim3(gxc, DFFN / BN), 256, 0, stream>>>(
            R2 + (size_t)ms * CDIM, W1, b1, W2, b2, nullptr, nullptr,
            R1, mc, DFFN, CDIM);
        // out = x + ls_ffn * (h @ W3^T + b3)
        gemm_kernel<2><<<dim3(gxc, CDIM / BN), 256, 0, stream>>>(
            R1, W3, b3, nullptr, nullptr, R0 + (size_t)ms * CDIM, ls_ffn,
            out + (size_t)ms * CDIM, mc, CDIM, DFFN);
    }
}

// Round 3
// 726.203 us; speedup vs baseline: 2.5076x; 2.5076x over previous
//
#include <hip/hip_runtime.h>
#include <hip/hip_bf16.h>
#include <cstddef>

// Problem constants (static shapes from the reference)
#define LQ   17821
#define BS   2
#define MTOK (BS * LQ)       // 35642 token rows
#define CDIM 256
#define NHD  8
#define DHEAD 32
#define DFFN 1024

typedef short bf16x4 __attribute__((ext_vector_type(4)));
typedef short bf16x8 __attribute__((ext_vector_type(8)));
typedef float f32x4  __attribute__((ext_vector_type(4)));

// ---------------------------------------------------------------------------
// fp32 -> bf16 cast (weights, once per launch)
// ---------------------------------------------------------------------------
__global__ __launch_bounds__(256)
void cast_kernel(const float* __restrict__ src, __hip_bfloat16* __restrict__ dst, int n) {
    const int i = blockIdx.x * 256 + threadIdx.x;
    if (i < n) dst[i] = (__hip_bfloat16)src[i];
}

// ---------------------------------------------------------------------------
// RMSNorm (+ optional pos-add producing q); bf16 outputs
// ---------------------------------------------------------------------------
template <bool ADD_POS>
__global__ __launch_bounds__(256)
void rmsnorm_kernel(const float* __restrict__ x, const float* __restrict__ pos,
                    const float* __restrict__ w,
                    __hip_bfloat16* __restrict__ outN, __hip_bfloat16* __restrict__ outQ) {
    const size_t base = (size_t)blockIdx.x * CDIM;
    const int c = threadIdx.x;
    const float v = x[base + c];
    float ss = v * v;
#pragma unroll
    for (int m = 1; m < 64; m <<= 1) ss += __shfl_xor(ss, m, 64);
    __shared__ float red[4];
    if ((threadIdx.x & 63) == 0) red[threadIdx.x >> 6] = ss;
    __syncthreads();
    const float tot = red[0] + red[1] + red[2] + red[3];
    const float r = rsqrtf(tot * (1.0f / CDIM) + 1e-6f);
    const float nv = v * r * w[c];
    outN[base + c] = (__hip_bfloat16)nv;
    if (ADD_POS) outQ[base + c] = (__hip_bfloat16)(nv + pos[base + c]);
}

// ---------------------------------------------------------------------------
// bf16 MFMA GEMM: C[M,N] = A[M,K] @ W[N,K]^T (+ epilogues), fp32 accumulate.
// 128x128 block tile, BK=32, 4 waves (2x2), each wave 4x4 of 16x16x32 MFMA.
// MODE 0: out = acc + bias1                          (plain)
// MODE 1: value layout write (b, h, q, c), bf16
// MODE 2: out = resid + ls * (acc + bias1)           (LayerScale residual)
// MODE 3: out = silu(acc1+bias1) * (acc2+bias2)      (SwiGLU, dual weights)
// N, K must be multiples of 128/32 resp. (true here); M guarded.
// ---------------------------------------------------------------------------
#define GBM 128
#define GBN 128
#define GBK 32
#define LDK 40   // padded LDS row stride in bf16 elems (80 B: 2-way bank alias = free)

__device__ __forceinline__ bf16x8 ld_frag(const short* p) {
    const bf16x4 lo = *(const bf16x4*)p;
    const bf16x4 hi = *(const bf16x4*)(p + 4);
    bf16x8 r;
    r[0] = lo[0]; r[1] = lo[1]; r[2] = lo[2]; r[3] = lo[3];
    r[4] = hi[0]; r[5] = hi[1]; r[6] = hi[2]; r[7] = hi[3];
    return r;
}

__device__ __forceinline__ void st_stage(short* p, uint4 v) {
    union { uint4 u; bf16x4 h[2]; } cv;
    cv.u = v;
    ((bf16x4*)p)[0] = cv.h[0];
    ((bf16x4*)p)[1] = cv.h[1];
}

template <int MODE, typename OUTT>
__global__ __launch_bounds__(256, 2)
void mfma_gemm(const __hip_bfloat16* __restrict__ A,
               const __hip_bfloat16* __restrict__ B1, const float* __restrict__ bias1,
               const __hip_bfloat16* __restrict__ B2, const float* __restrict__ bias2,
               const float* __restrict__ resid, const float* __restrict__ ls,
               OUTT* __restrict__ out, int M, int N, int K) {
    __shared__ short As[GBM * LDK];
    __shared__ short Bs[GBN * LDK];
    __shared__ short Bs2[(MODE == 3) ? GBN * LDK : 1];

    const int tid = threadIdx.x;
    const int m0 = blockIdx.x * GBM;
    const int n0 = blockIdx.y * GBN;
    const int wave = tid >> 6;
    const int lane = tid & 63;
    const int wm = (wave >> 1) * 64;
    const int wn = (wave & 1) * 64;
    const int fr = lane & 15;   // fragment row (m for A / n for B; col of C)
    const int fq = lane >> 4;   // quad: k = fq*8+j ; C row = fq*4+r

    f32x4 acc[4][4] = {};
    f32x4 acc2[(MODE == 3) ? 4 : 1][(MODE == 3) ? 4 : 1] = {};

    // staging map: 512 chunks of 8 bf16; chunk c: row=c>>2, kc=(c&3)*8
    const int srow = tid >> 2;
    const int skc = (tid & 3) * 8;

    for (int k0 = 0; k0 < K; k0 += GBK) {
        const uint4 zero4 = make_uint4(0, 0, 0, 0);
        const int gm0 = m0 + srow, gm1 = m0 + srow + 64;
        uint4 a0 = (gm0 < M) ? *(const uint4*)&A[(size_t)gm0 * K + k0 + skc] : zero4;
        uint4 a1 = (gm1 < M) ? *(const uint4*)&A[(size_t)gm1 * K + k0 + skc] : zero4;
        const uint4 b0 = *(const uint4*)&B1[(size_t)(n0 + srow) * K + k0 + skc];
        const uint4 b1 = *(const uint4*)&B1[(size_t)(n0 + srow + 64) * K + k0 + skc];
        uint4 c0, c1;
        if constexpr (MODE == 3) {
            c0 = *(const uint4*)&B2[(size_t)(n0 + srow) * K + k0 + skc];
            c1 = *(const uint4*)&B2[(size_t)(n0 + srow + 64) * K + k0 + skc];
        }
        __syncthreads();  // previous iter's compute done before LDS overwrite
        st_stage(&As[srow * LDK + skc], a0);
        st_stage(&As[(srow + 64) * LDK + skc], a1);
        st_stage(&Bs[srow * LDK + skc], b0);
        st_stage(&Bs[(srow + 64) * LDK + skc], b1);
        if constexpr (MODE == 3) {
            st_stage(&Bs2[srow * LDK + skc], c0);
            st_stage(&Bs2[(srow + 64) * LDK + skc], c1);
        }
        __syncthreads();

        bf16x8 af[4], bf[4];
#pragma unroll
        for (int i = 0; i < 4; ++i)
            af[i] = ld_frag(&As[(wm + i * 16 + fr) * LDK + fq * 8]);
#pragma unroll
        for (int j = 0; j < 4; ++j)
            bf[j] = ld_frag(&Bs[(wn + j * 16 + fr) * LDK + fq * 8]);
#pragma unroll
        for (int i = 0; i < 4; ++i)
#pragma unroll
            for (int j = 0; j < 4; ++j)
                acc[i][j] = __builtin_amdgcn_mfma_f32_16x16x32_bf16(af[i], bf[j], acc[i][j], 0, 0, 0);
        if constexpr (MODE == 3) {
            bf16x8 bg[4];
#pragma unroll
            for (int j = 0; j < 4; ++j)
                bg[j] = ld_frag(&Bs2[(wn + j * 16 + fr) * LDK + fq * 8]);
#pragma unroll
            for (int i = 0; i < 4; ++i)
#pragma unroll
                for (int j = 0; j < 4; ++j)
                    acc2[i][j] = __builtin_amdgcn_mfma_f32_16x16x32_bf16(af[i], bg[j], acc2[i][j], 0, 0, 0);
        }
    }

    // epilogue: C[m][n], m = m0+wm+i*16+fq*4+r, n = n0+wn+j*16+fr
#pragma unroll
    for (int i = 0; i < 4; ++i) {
#pragma unroll
        for (int r = 0; r < 4; ++r) {
            const int m = m0 + wm + i * 16 + fq * 4 + r;
            if (m >= M) continue;
#pragma unroll
            for (int j = 0; j < 4; ++j) {
                const int n = n0 + wn + j * 16 + fr;
                const float v = acc[i][j][r] + bias1[n];
                if constexpr (MODE == 0) {
                    out[(size_t)m * N + n] = (OUTT)v;
                } else if constexpr (MODE == 1) {
                    const int b = (m >= LQ) ? 1 : 0;
                    const int qi = m - b * LQ;
                    const int h = n >> 5;
                    const int c = n & 31;
                    out[((size_t)(b * NHD + h) * LQ + qi) * DHEAD + c] = (OUTT)v;
                } else if constexpr (MODE == 2) {
                    out[(size_t)m * N + n] =
                        (OUTT)(resid[(size_t)m * N + n] + ls[n] * v);
                } else {  // SwiGLU
                    const float sig = 1.0f / (1.0f + expf(-v));
                    const float v2 = acc2[i][j][r] + bias2[n];
                    out[(size_t)m * N + n] = (OUTT)(v * sig * v2);
                }
            }
        }
    }
}

// ---------------------------------------------------------------------------
// MSDeformAttn sampling, cooperative per-token block.
// Phase 1 (8 thr):   softmax of 16 logits per head -> LDS
// Phase 2 (128 thr): bilinear tap indices + combined weights -> LDS
// Phase 3 (256 thr): (h,c) gather-accumulate 64 bf16 taps
// value: bf16 (b,h,Lq,32). off: f32 (M,256). awl: bf16 (M,128).
// ref: f32 (bs,Lq,4,2). out: bf16 (M,256).
// ---------------------------------------------------------------------------
__global__ __launch_bounds__(256)
void sample_kernel(const __hip_bfloat16* __restrict__ value,
                   const float* __restrict__ off,
                   const __hip_bfloat16* __restrict__ awl,
                   const float* __restrict__ ref,
                   __hip_bfloat16* __restrict__ out) {
    __shared__ float wsm[NHD][16];
    __shared__ int   sIdx[128][4];
    __shared__ float sWt[128][4];

    const int row = blockIdx.x;
    const int b = (row >= LQ) ? 1 : 0;
    const int t = threadIdx.x;

    if (t < NHD) {
        const __hip_bfloat16* lg = &awl[(size_t)row * 128 + t * 16];
        float v[16];
        float mx = -3.4e38f;
#pragma unroll
        for (int i = 0; i < 16; ++i) { v[i] = (float)lg[i]; mx = fmaxf(mx, v[i]); }
        float s = 0.f;
#pragma unroll
        for (int i = 0; i < 16; ++i) { v[i] = expf(v[i] - mx); s += v[i]; }
        const float inv = 1.0f / s;
#pragma unroll
        for (int i = 0; i < 16; ++i) wsm[t][i] = v[i] * inv;
    }
    __syncthreads();

    if (t < 128) {
        const int h = t >> 4, pt = t & 15, lv = pt >> 2;
        const int Hs[4] = {100, 50, 25, 13};
        const int Ws[4] = {134, 67, 34, 17};
        const int st[4] = {0, 13400, 16750, 17600};
        const int H = Hs[lv], W = Ws[lv];
        const float rx = ref[((size_t)row * 4 + lv) * 2 + 0];
        const float ry = ref[((size_t)row * 4 + lv) * 2 + 1];
        const float ox = off[(size_t)row * 256 + h * 32 + pt * 2 + 0];
        const float oy = off[(size_t)row * 256 + h * 32 + pt * 2 + 1];
        const float xf = rx * (float)W + ox - 0.5f;
        const float yf = ry * (float)H + oy - 0.5f;
        const float x0f = floorf(xf), y0f = floorf(yf);
        const float fx = xf - x0f, fy = yf - y0f;
        const int x0 = (int)x0f, y0 = (int)y0f;
        const float aw = wsm[h][pt];
        const int base = (b * NHD + h) * LQ + st[lv];
#pragma unroll
        for (int tap = 0; tap < 4; ++tap) {
            const int dy = tap >> 1, dx = tap & 1;
            const int xi = x0 + dx, yi = y0 + dy;
            const bool valid = (xi >= 0) & (xi < W) & (yi >= 0) & (yi < H);
            const float wgt = (dx ? fx : 1.f - fx) * (dy ? fy : 1.f - fy) * aw;
            sIdx[t][tap] = valid ? (base + yi * W + xi) * DHEAD : 0;
            sWt[t][tap] = valid ? wgt : 0.f;
        }
    }
    __syncthreads();

    const int h = t >> 5, c = t & 31;
    float acc = 0.f;
#pragma unroll 4
    for (int pt = 0; pt < 16; ++pt) {
        const int s = h * 16 + pt;
#pragma unroll
        for (int tap = 0; tap < 4; ++tap) {
            acc += sWt[s][tap] * (float)value[(size_t)sIdx[s][tap] + c];
        }
    }
    out[(size_t)row * 256 + h * 32 + c] = (__hip_bfloat16)acc;
}

// ---------------------------------------------------------------------------
// Workspace plan (byte offsets; peak ~97.7 MB):
//   [0, MCb)                normed_bf -> sampled_bf -> h_bf chunk (fits exactly)
//   [MCb, 2MCb)             q_bf
//   [2MCb, 2MCb+MCb)        value_bf;      later x f32 at [2MCb, 2MCb+MCf)
//   [3MCb, 3MCb+MCf)        off f32;       later n2_bf at [2MCb+MCf, ...)
//   [3MCb+MCf, +M*128*2)    awl bf16
//   then bf16 weights (2 MB)
// ---------------------------------------------------------------------------
extern "C" void kernel_launch(void* const* d_in, const int* in_sizes, int n_in,
                              void* d_out, int out_size, void* d_ws, size_t ws_size,
                              hipStream_t stream) {
    const float* query      = (const float*)d_in[0];
    const float* query_pos  = (const float*)d_in[1];
    const float* ref        = (const float*)d_in[2];
    const float* norm_attn_w = (const float*)d_in[5];
    const float* Wv   = (const float*)d_in[6];
    const float* bv   = (const float*)d_in[7];
    const float* Woff = (const float*)d_in[8];
    const float* boff = (const float*)d_in[9];
    const float* Waw  = (const float*)d_in[10];
    const float* baw  = (const float*)d_in[11];
    const float* Wo   = (const float*)d_in[12];
    const float* bo   = (const float*)d_in[13];
    const float* ls_attn = (const float*)d_in[14];
    const float* norm_ffn_w = (const float*)d_in[15];
    const float* W1 = (const float*)d_in[16];
    const float* b1 = (const float*)d_in[17];
    const float* W2 = (const float*)d_in[18];
    const float* b2 = (const float*)d_in[19];
    const float* W3 = (const float*)d_in[20];
    const float* b3 = (const float*)d_in[21];
    const float* ls_ffn = (const float*)d_in[22];
    float* out = (float*)d_out;

    char* ws = (char*)d_ws;
    const size_t MCb = (size_t)MTOK * CDIM * 2;        // 18,248,704
    const size_t MCf = (size_t)MTOK * CDIM * 4;        // 36,497,408

    __hip_bfloat16* normed_bf  = (__hip_bfloat16*)(ws);
    __hip_bfloat16* q_bf       = (__hip_bfloat16*)(ws + MCb);
    __hip_bfloat16* sampled_bf = (__hip_bfloat16*)(ws);              // after normed dead
    __hip_bfloat16* h_bf       = (__hip_bfloat16*)(ws);              // FFN chunk (after sampled dead)
    __hip_bfloat16* value_bf   = (__hip_bfloat16*)(ws + 2 * MCb);
    float*          off_f      = (float*)(ws + 3 * MCb);
    __hip_bfloat16* awl_bf     = (__hip_bfloat16*)(ws + 3 * MCb + MCf);
    float*          x_f        = (float*)(ws + 2 * MCb);             // after value/off dead
    __hip_bfloat16* n2_bf      = (__hip_bfloat16*)(ws + 2 * MCb + MCf);
    __hip_bfloat16* wbf        = (__hip_bfloat16*)(ws + 3 * MCb + MCf + (size_t)MTOK * 128 * 2);

    __hip_bfloat16* Wv_bf   = wbf;
    __hip_bfloat16* Woff_bf = wbf + 65536;
    __hip_bfloat16* Waw_bf  = wbf + 131072;
    __hip_bfloat16* Wo_bf   = wbf + 163840;
    __hip_bfloat16* W1_bf   = wbf + 229376;
    __hip_bfloat16* W2_bf   = wbf + 491520;
    __hip_bfloat16* W3_bf   = wbf + 753664;

    // 0. weight casts
    cast_kernel<<<256, 256, 0, stream>>>(Wv,   Wv_bf,   65536);
    cast_kernel<<<256, 256, 0, stream>>>(Woff, Woff_bf, 65536);
    cast_kernel<<<128, 256, 0, stream>>>(Waw,  Waw_bf,  32768);
    cast_kernel<<<256, 256, 0, stream>>>(Wo,   Wo_bf,   65536);
    cast_kernel<<<1024, 256, 0, stream>>>(W1,  W1_bf,  262144);
    cast_kernel<<<1024, 256, 0, stream>>>(W2,  W2_bf,  262144);
    cast_kernel<<<1024, 256, 0, stream>>>(W3,  W3_bf,  262144);

    const int gx = (MTOK + GBM - 1) / GBM;  // 279

    // 1. normed_bf, q_bf = normed + pos
    rmsnorm_kernel<true><<<MTOK, 256, 0, stream>>>(query, query_pos, norm_attn_w, normed_bf, q_bf);
    // 2. value = normed @ Wv^T + bv -> bf16 (b,h,q,c)
    mfma_gemm<1, __hip_bfloat16><<<dim3(gx, 2), 256, 0, stream>>>(
        normed_bf, Wv_bf, bv, nullptr, nullptr, nullptr, nullptr, value_bf, MTOK, CDIM, CDIM);
    // 3. off = q @ Woff^T + boff -> f32
    mfma_gemm<0, float><<<dim3(gx, 2), 256, 0, stream>>>(
        q_bf, Woff_bf, boff, nullptr, nullptr, nullptr, nullptr, off_f, MTOK, 256, CDIM);
    // 4. awl = q @ Waw^T + baw -> bf16
    mfma_gemm<0, __hip_bfloat16><<<dim3(gx, 1), 256, 0, stream>>>(
        q_bf, Waw_bf, baw, nullptr, nullptr, nullptr, nullptr, awl_bf, MTOK, 128, CDIM);
    // 5. deformable sampling -> sampled_bf
    sample_kernel<<<MTOK, 256, 0, stream>>>(value_bf, off_f, awl_bf, ref, sampled_bf);
    // 6. x = query + ls_attn * (sampled @ Wo^T + bo) -> f32
    mfma_gemm<2, float><<<dim3(gx, 2), 256, 0, stream>>>(
        sampled_bf, Wo_bf, bo, nullptr, nullptr, query, ls_attn, x_f, MTOK, CDIM, CDIM);
    // 7. n2 = rmsnorm(x) -> bf16
    rmsnorm_kernel<false><<<MTOK, 256, 0, stream>>>(x_f, nullptr, norm_ffn_w, n2_bf, nullptr);
    // 8/9. FFN in 2 chunks of LQ rows (h chunk fits exactly in [0, MCb))
    for (int ms = 0; ms < MTOK; ms += LQ) {
        const int mc = LQ;
        const int gxc = (mc + GBM - 1) / GBM;  // 140
        mfma_gemm<3, __hip_bfloat16><<<dim3(gxc, DFFN / GBN), 256, 0, stream>>>(
            n2_bf + (size_t)ms * CDIM, W1_bf, b1, W2_bf, b2, nullptr, nullptr,
            h_bf, mc, DFFN, CDIM);
        mfma_gemm<2, float><<<dim3(gxc, 2), 256, 0, stream>>>(
            h_bf, W3_bf, b3, nullptr, nullptr, x_f + (size_t)ms * CDIM, ls_ffn,
            out + (size_t)ms * CDIM, mc, CDIM, DFFN);
    }
}

// Round 5
// 639.937 us; speedup vs baseline: 2.8457x; 1.1348x over previous
//
#include <hip/hip_runtime.h>
#include <hip/hip_bf16.h>
#include <cstddef>

// Problem constants (static shapes from the reference)
#define LQ   17821
#define BS   2
#define MTOK (BS * LQ)       // 35642 token rows
#define CDIM 256
#define NHD  8
#define DHEAD 32
#define DFFN 1024

typedef short bf16x4 __attribute__((ext_vector_type(4)));
typedef short bf16x8 __attribute__((ext_vector_type(8)));
typedef float f32x4  __attribute__((ext_vector_type(4)));

// ---------------------------------------------------------------------------
// Batched fp32 -> bf16 weight cast (single dispatch)
// ---------------------------------------------------------------------------
struct CastJobs {
    const float* src[7];
    __hip_bfloat16* dst[7];
    int n[7];
};

__global__ __launch_bounds__(256)
void cast_all(CastJobs j) {
    const int seg = blockIdx.y;
    const int i = blockIdx.x * 256 + threadIdx.x;
    if (i < j.n[seg]) j.dst[seg][i] = (__hip_bfloat16)j.src[seg][i];
}

// ---------------------------------------------------------------------------
// RMSNorm, wave-per-token (64 lanes x float4 = 256 ch), 4 tokens/block.
// ---------------------------------------------------------------------------
__device__ __forceinline__ ushort bfpack(float f) {
    __hip_bfloat16 h = (__hip_bfloat16)f;
    return *(ushort*)&h;
}

template <bool ADD_POS>
__global__ __launch_bounds__(256)
void rmsnorm_kernel(const float* __restrict__ x, const float* __restrict__ pos,
                    const float* __restrict__ w,
                    __hip_bfloat16* __restrict__ outN, __hip_bfloat16* __restrict__ outQ) {
    const int tok = blockIdx.x * 4 + (threadIdx.x >> 6);
    if (tok >= MTOK) return;
    const int lane = threadIdx.x & 63;
    const size_t base = (size_t)tok * CDIM + lane * 4;
    const float4 v = *(const float4*)&x[base];
    float ss = v.x * v.x + v.y * v.y + v.z * v.z + v.w * v.w;
#pragma unroll
    for (int m = 1; m < 64; m <<= 1) ss += __shfl_xor(ss, m, 64);
    const float r = rsqrtf(ss * (1.0f / CDIM) + 1e-6f);
    const float4 wv = *(const float4*)&w[lane * 4];
    const float n0 = v.x * r * wv.x, n1 = v.y * r * wv.y;
    const float n2 = v.z * r * wv.z, n3 = v.w * r * wv.w;
    ushort4 o;
    o.x = bfpack(n0); o.y = bfpack(n1); o.z = bfpack(n2); o.w = bfpack(n3);
    *(ushort4*)&outN[base] = o;
    if (ADD_POS) {
        const float4 p = *(const float4*)&pos[base];
        ushort4 q;
        q.x = bfpack(n0 + p.x); q.y = bfpack(n1 + p.y);
        q.z = bfpack(n2 + p.z); q.w = bfpack(n3 + p.w);
        *(ushort4*)&outQ[base] = q;
    }
}

// ---------------------------------------------------------------------------
// bf16 MFMA GEMM: C[M,N] = A[M,K] @ W[N,K]^T (+ epilogues), fp32 accumulate.
// 128x128 block tile, BK=32, 4 waves (2x2), each wave 4x4 of 16x16x32 MFMA.
// Register-prefetch pipeline: tile k+1 loads issue before tile-k MFMAs.
// MODE 0: out = acc + bias1
// MODE 1: value layout write (b, h, q, c), bf16
// MODE 2: out = resid + ls * (acc + bias1)
// MODE 3: out = silu(acc1+bias1) * (acc2+bias2)   (dual weights)
// MODE 4: out = acc + concat(bias1[0:256], bias2[0:128])[n]   (proj N=384)
// ---------------------------------------------------------------------------
#define GBM 128
#define GBN 128
#define GBK 32
#define LDK 40   // padded LDS row stride (80 B: 2-way bank alias = free)

__device__ __forceinline__ bf16x8 ld_frag(const short* p) {
    const bf16x4 lo = *(const bf16x4*)p;
    const bf16x4 hi = *(const bf16x4*)(p + 4);
    bf16x8 r;
    r[0] = lo[0]; r[1] = lo[1]; r[2] = lo[2]; r[3] = lo[3];
    r[4] = hi[0]; r[5] = hi[1]; r[6] = hi[2]; r[7] = hi[3];
    return r;
}

__device__ __forceinline__ void st_stage(short* p, uint4 v) {
    union { uint4 u; bf16x4 h[2]; } cv;
    cv.u = v;
    ((bf16x4*)p)[0] = cv.h[0];
    ((bf16x4*)p)[1] = cv.h[1];
}

template <int MODE, typename OUTT>
__global__ __launch_bounds__(256, 2)
void mfma_gemm(const __hip_bfloat16* __restrict__ A,
               const __hip_bfloat16* __restrict__ B1, const float* __restrict__ bias1,
               const __hip_bfloat16* __restrict__ B2, const float* __restrict__ bias2,
               const float* __restrict__ resid, const float* __restrict__ ls,
               OUTT* __restrict__ out, int M, int N, int K) {
    __shared__ short As[GBM * LDK];
    __shared__ short Bs[GBN * LDK];
    __shared__ short Bs2[(MODE == 3) ? GBN * LDK : 1];

    const int tid = threadIdx.x;
    const int m0 = blockIdx.x * GBM;
    const int n0 = blockIdx.y * GBN;
    const int wave = tid >> 6;
    const int lane = tid & 63;
    const int wm = (wave >> 1) * 64;
    const int wn = (wave & 1) * 64;
    const int fr = lane & 15;   // col of C
    const int fq = lane >> 4;   // quad: k = fq*8+j ; C row = fq*4+r

    f32x4 acc[4][4] = {};
    f32x4 acc2[(MODE == 3) ? 4 : 1][(MODE == 3) ? 4 : 1] = {};

    // staging map: 512 chunks of 8 bf16
    const int srow = tid >> 2;
    const int skc = (tid & 3) * 8;
    const uint4 zero4 = make_uint4(0, 0, 0, 0);

    uint4 ra0, ra1, rb0, rb1, rc0 = zero4, rc1 = zero4;
    {   // prologue: tile 0
        const int gm0 = m0 + srow, gm1 = m0 + srow + 64;
        ra0 = (gm0 < M) ? *(const uint4*)&A[(size_t)gm0 * K + skc] : zero4;
        ra1 = (gm1 < M) ? *(const uint4*)&A[(size_t)gm1 * K + skc] : zero4;
        rb0 = *(const uint4*)&B1[(size_t)(n0 + srow) * K + skc];
        rb1 = *(const uint4*)&B1[(size_t)(n0 + srow + 64) * K + skc];
        if constexpr (MODE == 3) {
            rc0 = *(const uint4*)&B2[(size_t)(n0 + srow) * K + skc];
            rc1 = *(const uint4*)&B2[(size_t)(n0 + srow + 64) * K + skc];
        }
    }

    for (int k0 = 0; k0 < K; k0 += GBK) {
        __syncthreads();   // prev tile's LDS reads done
        st_stage(&As[srow * LDK + skc], ra0);
        st_stage(&As[(srow + 64) * LDK + skc], ra1);
        st_stage(&Bs[srow * LDK + skc], rb0);
        st_stage(&Bs[(srow + 64) * LDK + skc], rb1);
        if constexpr (MODE == 3) {
            st_stage(&Bs2[srow * LDK + skc], rc0);
            st_stage(&Bs2[(srow + 64) * LDK + skc], rc1);
        }
        __syncthreads();

        if (k0 + GBK < K) {   // issue next-tile loads; latency overlaps MFMA below
            const int kn = k0 + GBK + skc;
            const int gm0 = m0 + srow, gm1 = m0 + srow + 64;
            ra0 = (gm0 < M) ? *(const uint4*)&A[(size_t)gm0 * K + kn] : zero4;
            ra1 = (gm1 < M) ? *(const uint4*)&A[(size_t)gm1 * K + kn] : zero4;
            rb0 = *(const uint4*)&B1[(size_t)(n0 + srow) * K + kn];
            rb1 = *(const uint4*)&B1[(size_t)(n0 + srow + 64) * K + kn];
            if constexpr (MODE == 3) {
                rc0 = *(const uint4*)&B2[(size_t)(n0 + srow) * K + kn];
                rc1 = *(const uint4*)&B2[(size_t)(n0 + srow + 64) * K + kn];
            }
        }

        bf16x8 af[4], bfr[4];
#pragma unroll
        for (int i = 0; i < 4; ++i)
            af[i] = ld_frag(&As[(wm + i * 16 + fr) * LDK + fq * 8]);
#pragma unroll
        for (int j = 0; j < 4; ++j)
            bfr[j] = ld_frag(&Bs[(wn + j * 16 + fr) * LDK + fq * 8]);
#pragma unroll
        for (int i = 0; i < 4; ++i)
#pragma unroll
            for (int j = 0; j < 4; ++j)
                acc[i][j] = __builtin_amdgcn_mfma_f32_16x16x32_bf16(af[i], bfr[j], acc[i][j], 0, 0, 0);
        if constexpr (MODE == 3) {
            bf16x8 bg[4];
#pragma unroll
            for (int j = 0; j < 4; ++j)
                bg[j] = ld_frag(&Bs2[(wn + j * 16 + fr) * LDK + fq * 8]);
#pragma unroll
            for (int i = 0; i < 4; ++i)
#pragma unroll
                for (int j = 0; j < 4; ++j)
                    acc2[i][j] = __builtin_amdgcn_mfma_f32_16x16x32_bf16(af[i], bg[j], acc2[i][j], 0, 0, 0);
        }
    }

    // epilogue: C[m][n], m = m0+wm+i*16+fq*4+r, n = n0+wn+j*16+fr
#pragma unroll
    for (int i = 0; i < 4; ++i) {
#pragma unroll
        for (int r = 0; r < 4; ++r) {
            const int m = m0 + wm + i * 16 + fq * 4 + r;
            if (m >= M) continue;
#pragma unroll
            for (int j = 0; j < 4; ++j) {
                const int n = n0 + wn + j * 16 + fr;
                float v;
                if constexpr (MODE == 4)
                    v = acc[i][j][r] + ((n < 256) ? bias1[n] : bias2[n - 256]);
                else
                    v = acc[i][j][r] + bias1[n];
                if constexpr (MODE == 0 || MODE == 4) {
                    out[(size_t)m * N + n] = (OUTT)v;
                } else if constexpr (MODE == 1) {
                    const int b = (m >= LQ) ? 1 : 0;
                    const int qi = m - b * LQ;
                    const int h = n >> 5;
                    const int c = n & 31;
                    out[((size_t)(b * NHD + h) * LQ + qi) * DHEAD + c] = (OUTT)v;
                } else if constexpr (MODE == 2) {
                    out[(size_t)m * N + n] =
                        (OUTT)(resid[(size_t)m * N + n] + ls[n] * v);
                } else {  // MODE 3 SwiGLU
                    const float sig = 1.0f / (1.0f + expf(-v));
                    const float v2 = acc2[i][j][r] + bias2[n];
                    out[(size_t)m * N + n] = (OUTT)(v * sig * v2);
                }
            }
        }
    }
}

// ---------------------------------------------------------------------------
// MSDeformAttn sampling v2: 4 tokens/block (one wave each).
// Phase 1 (32 thr):  softmax of 16 logits per (token, head) -> LDS
// Phase 2 (256 thr): tap (idx, weight) as int2 -> LDS [64][9] (stride-9 pad)
// Phase 3: lane = (h, 4 channels); dwordx2 gather (4 bf16) + 4 FMA per tap.
// proj: f32 (M,384): cols 0..255 = offsets, 256..383 = aw logits.
// value: bf16 (b,h,Lq,32).  out: bf16 (M,256).
// ---------------------------------------------------------------------------
__global__ __launch_bounds__(256)
void sample_kernel(const __hip_bfloat16* __restrict__ value,
                   const float* __restrict__ proj,
                   const float* __restrict__ ref,
                   __hip_bfloat16* __restrict__ out) {
    __shared__ float wsm[4][NHD][16];
    __shared__ int2  sTap[4][64][9];   // [token][pt*4+tap][head], slot 8 = pad

    const int tok0 = blockIdx.x * 4;
    const int t = threadIdx.x;

    if (t < 32) {
        const int tl = t >> 3, h = t & 7;
        const int row = tok0 + tl;
        if (row < MTOK) {
            const float* lg = &proj[(size_t)row * 384 + 256 + h * 16];
            float v[16];
            float mx = -3.4e38f;
#pragma unroll
            for (int i = 0; i < 16; ++i) { v[i] = lg[i]; mx = fmaxf(mx, v[i]); }
            float s = 0.f;
#pragma unroll
            for (int i = 0; i < 16; ++i) { v[i] = expf(v[i] - mx); s += v[i]; }
            const float inv = 1.0f / s;
#pragma unroll
            for (int i = 0; i < 16; ++i) wsm[tl][h][i] = v[i] * inv;
        }
    }
    __syncthreads();

#pragma unroll
    for (int e = t; e < 512; e += 256) {
        const int tl = e >> 7, hp = e & 127;
        const int row = tok0 + tl;
        if (row < MTOK) {
            const int h = hp >> 4, pt = hp & 15, lv = pt >> 2;
            const int Hs[4] = {100, 50, 25, 13};
            const int Ws[4] = {134, 67, 34, 17};
            const int stt[4] = {0, 13400, 16750, 17600};
            const int H = Hs[lv], W = Ws[lv];
            const float rx = ref[((size_t)row * 4 + lv) * 2 + 0];
            const float ry = ref[((size_t)row * 4 + lv) * 2 + 1];
            const float ox = proj[(size_t)row * 384 + h * 32 + pt * 2 + 0];
            const float oy = proj[(size_t)row * 384 + h * 32 + pt * 2 + 1];
            const float xf = rx * (float)W + ox - 0.5f;
            const float yf = ry * (float)H + oy - 0.5f;
            const float x0f = floorf(xf), y0f = floorf(yf);
            const float fx = xf - x0f, fy = yf - y0f;
            const int x0 = (int)x0f, y0 = (int)y0f;
            const float aw = wsm[tl][h][pt];
            const int b = (row >= LQ) ? 1 : 0;
            const int base = (b * NHD + h) * LQ + stt[lv];
#pragma unroll
            for (int tap = 0; tap < 4; ++tap) {
                const int dy = tap >> 1, dx = tap & 1;
                const int xi = x0 + dx, yi = y0 + dy;
                const bool valid = (xi >= 0) & (xi < W) & (yi >= 0) & (yi < H);
                const float wgt = (dx ? fx : 1.f - fx) * (dy ? fy : 1.f - fy) * aw;
                sTap[tl][pt * 4 + tap][h] = valid
                    ? make_int2((base + yi * W + xi) * DHEAD, __float_as_int(wgt))
                    : make_int2(0, 0);
            }
        }
    }
    __syncthreads();

    const int tl = t >> 6, lane = t & 63;
    const int row = tok0 + tl;
    if (row >= MTOK) return;
    const int h = lane >> 3, c0 = (lane & 7) * 4;
    const char* vb = (const char*)value + (size_t)c0 * 2;
    float a0 = 0.f, a1 = 0.f, a2 = 0.f, a3 = 0.f;
#pragma unroll 8
    for (int i = 0; i < 64; ++i) {
        const int2 tp = sTap[tl][i][h];
        const float w = __int_as_float(tp.y);
        const uint2 d = *(const uint2*)(vb + (size_t)tp.x * 2);
        a0 = fmaf(w, __int_as_float(d.x << 16), a0);
        a1 = fmaf(w, __int_as_float(d.x & 0xffff0000u), a1);
        a2 = fmaf(w, __int_as_float(d.y << 16), a2);
        a3 = fmaf(w, __int_as_float(d.y & 0xffff0000u), a3);
    }
    ushort4 o;
    o.x = bfpack(a0); o.y = bfpack(a1); o.z = bfpack(a2); o.w = bfpack(a3);
    *(ushort4*)&out[(size_t)row * 256 + h * 32 + c0] = o;
}

// ---------------------------------------------------------------------------
// Workspace (bytes; peak ~111.5 MB). MCb = 18.25 MB, MCf = 36.5 MB.
//   [0, MCb)              normed -> sampled (dead after step 5)
//   [MCb, 2MCb)           q -> n2
//   [2MCb, 3MCb)          value (dead after step 4)
//   [2MCb, 2MCb+MCf)      x_f  (written step 5, over dead value + proj head)
//   [3MCb, 3MCb+54.7MB)   proj f32 (dead after step 4)
//   [4MCb, 4MCb+MCf)      h_bf chunk — NOTE: starts at 4MCb (73.0 MB), NOT
//                         3MCb; at 3MCb it would clobber x_f rows [LQ,2LQ)
//                         (the R4 bug: absmax 5.4 from destroyed residual).
//   [109.5MB, +2MB)       bf16 weights
// ---------------------------------------------------------------------------
extern "C" void kernel_launch(void* const* d_in, const int* in_sizes, int n_in,
                              void* d_out, int out_size, void* d_ws, size_t ws_size,
                              hipStream_t stream) {
    const float* query      = (const float*)d_in[0];
    const float* query_pos  = (const float*)d_in[1];
    const float* ref        = (const float*)d_in[2];
    const float* norm_attn_w = (const float*)d_in[5];
    const float* Wv   = (const float*)d_in[6];
    const float* bv   = (const float*)d_in[7];
    const float* Woff = (const float*)d_in[8];
    const float* boff = (const float*)d_in[9];
    const float* Waw  = (const float*)d_in[10];
    const float* baw  = (const float*)d_in[11];
    const float* Wo   = (const float*)d_in[12];
    const float* bo   = (const float*)d_in[13];
    const float* ls_attn = (const float*)d_in[14];
    const float* norm_ffn_w = (const float*)d_in[15];
    const float* W1 = (const float*)d_in[16];
    const float* b1 = (const float*)d_in[17];
    const float* W2 = (const float*)d_in[18];
    const float* b2 = (const float*)d_in[19];
    const float* W3 = (const float*)d_in[20];
    const float* b3 = (const float*)d_in[21];
    const float* ls_ffn = (const float*)d_in[22];
    float* out = (float*)d_out;

    char* ws = (char*)d_ws;
    const size_t MCb = (size_t)MTOK * CDIM * 2;   // 18,248,704
    const size_t MCf = (size_t)MTOK * CDIM * 4;   // 36,497,408

    __hip_bfloat16* normed_bf  = (__hip_bfloat16*)(ws);
    __hip_bfloat16* q_bf       = (__hip_bfloat16*)(ws + MCb);
    __hip_bfloat16* value_bf   = (__hip_bfloat16*)(ws + 2 * MCb);
    float*          proj_f     = (float*)(ws + 3 * MCb);            // M x 384
    __hip_bfloat16* sampled_bf = (__hip_bfloat16*)(ws);             // after normed/q dead
    float*          x_f        = (float*)(ws + 2 * MCb);            // after value dead
    __hip_bfloat16* n2_bf      = (__hip_bfloat16*)(ws + MCb);       // after q dead
    __hip_bfloat16* h_bf       = (__hip_bfloat16*)(ws + 4 * MCb);   // after x_f end! (R4 fix)
    __hip_bfloat16* wbf        = (__hip_bfloat16*)(ws + 3 * MCb + (size_t)MTOK * 384 * 4);

    __hip_bfloat16* Wv_bf    = wbf;
    __hip_bfloat16* Wproj_bf = wbf + 65536;    // Woff (256 rows) ++ Waw (128 rows)
    __hip_bfloat16* Wo_bf    = wbf + 163840;
    __hip_bfloat16* W1_bf    = wbf + 229376;
    __hip_bfloat16* W2_bf    = wbf + 491520;
    __hip_bfloat16* W3_bf    = wbf + 753664;

    // 0. all weight casts in one dispatch
    CastJobs cj;
    cj.src[0] = Wv;   cj.dst[0] = Wv_bf;           cj.n[0] = 65536;
    cj.src[1] = Woff; cj.dst[1] = Wproj_bf;        cj.n[1] = 65536;
    cj.src[2] = Waw;  cj.dst[2] = Wproj_bf + 65536; cj.n[2] = 32768;
    cj.src[3] = Wo;   cj.dst[3] = Wo_bf;           cj.n[3] = 65536;
    cj.src[4] = W1;   cj.dst[4] = W1_bf;           cj.n[4] = 262144;
    cj.src[5] = W2;   cj.dst[5] = W2_bf;           cj.n[5] = 262144;
    cj.src[6] = W3;   cj.dst[6] = W3_bf;           cj.n[6] = 262144;
    cast_all<<<dim3(1024, 7), 256, 0, stream>>>(cj);

    const int gx = (MTOK + GBM - 1) / GBM;   // 279
    const int gr = (MTOK + 3) / 4;           // 8911

    // 1. normed_bf, q_bf = normed + pos
    rmsnorm_kernel<true><<<gr, 256, 0, stream>>>(query, query_pos, norm_attn_w, normed_bf, q_bf);
    // 2. value = normed @ Wv^T + bv -> bf16 (b,h,q,c)
    mfma_gemm<1, __hip_bfloat16><<<dim3(gx, 2), 256, 0, stream>>>(
        normed_bf, Wv_bf, bv, nullptr, nullptr, nullptr, nullptr, value_bf, MTOK, CDIM, CDIM);
    // 3. proj = q @ [Woff;Waw]^T + [boff;baw] -> f32 (M,384)
    mfma_gemm<4, float><<<dim3(gx, 3), 256, 0, stream>>>(
        q_bf, Wproj_bf, boff, nullptr, baw, nullptr, nullptr, proj_f, MTOK, 384, CDIM);
    // 4. deformable sampling -> sampled_bf
    sample_kernel<<<gr, 256, 0, stream>>>(value_bf, proj_f, ref, sampled_bf);
    // 5. x = query + ls_attn * (sampled @ Wo^T + bo) -> f32
    mfma_gemm<2, float><<<dim3(gx, 2), 256, 0, stream>>>(
        sampled_bf, Wo_bf, bo, nullptr, nullptr, query, ls_attn, x_f, MTOK, CDIM, CDIM);
    // 6. n2 = rmsnorm(x) -> bf16
    rmsnorm_kernel<false><<<gr, 256, 0, stream>>>(x_f, nullptr, norm_ffn_w, n2_bf, nullptr);
    // 7/8. FFN in 2 chunks of LQ rows (h chunk = 36.5 MB at [4MCb, 4MCb+MCf))
    for (int ms = 0; ms < MTOK; ms += LQ) {
        const int mc = LQ;
        const int gxc = (mc + GBM - 1) / GBM;  // 140
        mfma_gemm<3, __hip_bfloat16><<<dim3(gxc, DFFN / GBN), 256, 0, stream>>>(
            n2_bf + (size_t)ms * CDIM, W1_bf, b1, W2_bf, b2, nullptr, nullptr,
            h_bf, mc, DFFN, CDIM);
        mfma_gemm<2, float><<<dim3(gxc, 2), 256, 0, stream>>>(
            h_bf, W3_bf, b3, nullptr, nullptr, x_f + (size_t)ms * CDIM, ls_ffn,
            out + (size_t)ms * CDIM, mc, CDIM, DFFN);
    }
}

// Round 6
// 468.061 us; speedup vs baseline: 3.8906x; 1.3672x over previous
//
#include <hip/hip_runtime.h>
#include <hip/hip_bf16.h>
#include <cstddef>

// Problem constants (static shapes from the reference)
#define LQ   17821
#define BS   2
#define MTOK (BS * LQ)       // 35642 token rows
#define CDIM 256
#define NHD  8
#define DHEAD 32
#define DFFN 1024

typedef short bf16x4 __attribute__((ext_vector_type(4)));
typedef short bf16x8 __attribute__((ext_vector_type(8)));
typedef float f32x4  __attribute__((ext_vector_type(4)));

// ---------------------------------------------------------------------------
// Batched fp32 -> bf16 weight cast (single dispatch)
// ---------------------------------------------------------------------------
struct CastJobs {
    const float* src[7];
    __hip_bfloat16* dst[7];
    int n[7];
};

__global__ __launch_bounds__(256)
void cast_all(CastJobs j) {
    const int seg = blockIdx.y;
    const int i = blockIdx.x * 256 + threadIdx.x;
    if (i < j.n[seg]) j.dst[seg][i] = (__hip_bfloat16)j.src[seg][i];
}

// ---------------------------------------------------------------------------
// RMSNorm, wave-per-token (64 lanes x float4 = 256 ch), 4 tokens/block.
// ---------------------------------------------------------------------------
__device__ __forceinline__ ushort bfpack(float f) {
    __hip_bfloat16 h = (__hip_bfloat16)f;
    return *(ushort*)&h;
}

template <bool ADD_POS>
__global__ __launch_bounds__(256)
void rmsnorm_kernel(const float* __restrict__ x, const float* __restrict__ pos,
                    const float* __restrict__ w,
                    __hip_bfloat16* __restrict__ outN, __hip_bfloat16* __restrict__ outQ) {
    const int tok = blockIdx.x * 4 + (threadIdx.x >> 6);
    if (tok >= MTOK) return;
    const int lane = threadIdx.x & 63;
    const size_t base = (size_t)tok * CDIM + lane * 4;
    const float4 v = *(const float4*)&x[base];
    float ss = v.x * v.x + v.y * v.y + v.z * v.z + v.w * v.w;
#pragma unroll
    for (int m = 1; m < 64; m <<= 1) ss += __shfl_xor(ss, m, 64);
    const float r = rsqrtf(ss * (1.0f / CDIM) + 1e-6f);
    const float4 wv = *(const float4*)&w[lane * 4];
    const float n0 = v.x * r * wv.x, n1 = v.y * r * wv.y;
    const float n2 = v.z * r * wv.z, n3 = v.w * r * wv.w;
    ushort4 o;
    o.x = bfpack(n0); o.y = bfpack(n1); o.z = bfpack(n2); o.w = bfpack(n3);
    *(ushort4*)&outN[base] = o;
    if (ADD_POS) {
        const float4 p = *(const float4*)&pos[base];
        ushort4 q;
        q.x = bfpack(n0 + p.x); q.y = bfpack(n1 + p.y);
        q.z = bfpack(n2 + p.z); q.w = bfpack(n3 + p.w);
        *(ushort4*)&outQ[base] = q;
    }
}

// ---------------------------------------------------------------------------
// bf16 MFMA GEMM: C[M,N] = A[M,K] @ W[N,K]^T (+ epilogues), fp32 accumulate.
// 128x128 block tile, templated BK (32 or 64), 4 waves (2x2), each wave 4x4
// of 16x16x32 MFMA per 32-wide k-step. Register-prefetch pipeline.
// MODE 0: out = acc + bias1
// MODE 1: value layout write (b, h, q, c), bf16
// MODE 2: out = resid + ls * (acc + bias1)
// MODE 3: out = silu(acc1+bias1) * (acc2+bias2)   (dual weights, BK=32)
// MODE 4: out = acc + concat(bias1[0:256], bias2[0:128])[n]   (proj N=384)
// ---------------------------------------------------------------------------
#define GBM 128
#define GBN 128

template <int MODE, int BKT, typename OUTT>
__global__ __launch_bounds__(256, 2)
void mfma_gemm(const __hip_bfloat16* __restrict__ A,
               const __hip_bfloat16* __restrict__ B1, const float* __restrict__ bias1,
               const __hip_bfloat16* __restrict__ B2, const float* __restrict__ bias2,
               const float* __restrict__ resid, const float* __restrict__ ls,
               OUTT* __restrict__ out, int M, int N, int K) {
    constexpr int LDKT = BKT + 8;        // +16B pad: 2-way bank alias (free)
    constexpr int CH = BKT / 16;         // uint4 staging chunks per thread per matrix
    constexpr int CPR = BKT / 8;         // 8-elem chunks per row

    __shared__ short As[GBM * LDKT];
    __shared__ short Bs[GBN * LDKT];
    __shared__ short Bs2[(MODE == 3) ? GBN * LDKT : 1];

    const int tid = threadIdx.x;
    const int m0 = blockIdx.x * GBM;
    const int n0 = blockIdx.y * GBN;
    const int wave = tid >> 6;
    const int lane = tid & 63;
    const int wm = (wave >> 1) * 64;
    const int wn = (wave & 1) * 64;
    const int fr = lane & 15;   // col of C
    const int fq = lane >> 4;   // quad: k = fq*8+j ; C row = fq*4+r

    f32x4 acc[4][4] = {};
    f32x4 acc2[(MODE == 3) ? 4 : 1][(MODE == 3) ? 4 : 1] = {};

    // staging map: chunk g = tid + cc*256; row = g / CPR, kc = (g % CPR) * 8
    int srow[CH], skc[CH];
#pragma unroll
    for (int cc = 0; cc < CH; ++cc) {
        const int g = tid + cc * 256;
        srow[cc] = g / CPR;
        skc[cc] = (g % CPR) * 8;
    }
    const uint4 zero4 = make_uint4(0, 0, 0, 0);

    uint4 ra[CH], rb[CH], rc[(MODE == 3) ? CH : 1];
#pragma unroll
    for (int cc = 0; cc < CH; ++cc) {
        const int gm = m0 + srow[cc];
        ra[cc] = (gm < M) ? *(const uint4*)&A[(size_t)gm * K + skc[cc]] : zero4;
        rb[cc] = *(const uint4*)&B1[(size_t)(n0 + srow[cc]) * K + skc[cc]];
        if constexpr (MODE == 3)
            rc[cc] = *(const uint4*)&B2[(size_t)(n0 + srow[cc]) * K + skc[cc]];
    }

    for (int k0 = 0; k0 < K; k0 += BKT) {
        __syncthreads();   // prev tile's LDS reads done
#pragma unroll
        for (int cc = 0; cc < CH; ++cc) {
            short* pa = &As[srow[cc] * LDKT + skc[cc]];
            short* pb = &Bs[srow[cc] * LDKT + skc[cc]];
            union { uint4 u; bf16x4 h[2]; } cv;
            cv.u = ra[cc]; ((bf16x4*)pa)[0] = cv.h[0]; ((bf16x4*)pa)[1] = cv.h[1];
            cv.u = rb[cc]; ((bf16x4*)pb)[0] = cv.h[0]; ((bf16x4*)pb)[1] = cv.h[1];
            if constexpr (MODE == 3) {
                short* pc = &Bs2[srow[cc] * LDKT + skc[cc]];
                cv.u = rc[cc]; ((bf16x4*)pc)[0] = cv.h[0]; ((bf16x4*)pc)[1] = cv.h[1];
            }
        }
        __syncthreads();

        if (k0 + BKT < K) {   // issue next-tile loads; latency overlaps MFMAs below
            const int kn = k0 + BKT;
#pragma unroll
            for (int cc = 0; cc < CH; ++cc) {
                const int gm = m0 + srow[cc];
                ra[cc] = (gm < M) ? *(const uint4*)&A[(size_t)gm * K + kn + skc[cc]] : zero4;
                rb[cc] = *(const uint4*)&B1[(size_t)(n0 + srow[cc]) * K + kn + skc[cc]];
                if constexpr (MODE == 3)
                    rc[cc] = *(const uint4*)&B2[(size_t)(n0 + srow[cc]) * K + kn + skc[cc]];
            }
        }

#pragma unroll
        for (int kk = 0; kk < BKT; kk += 32) {
            const int kq = kk + fq * 8;
            bf16x8 af[4], bfr[4];
#pragma unroll
            for (int i = 0; i < 4; ++i)
                af[i] = *(const bf16x8*)&As[(wm + i * 16 + fr) * LDKT + kq];
#pragma unroll
            for (int j = 0; j < 4; ++j)
                bfr[j] = *(const bf16x8*)&Bs[(wn + j * 16 + fr) * LDKT + kq];
#pragma unroll
            for (int i = 0; i < 4; ++i)
#pragma unroll
                for (int j = 0; j < 4; ++j)
                    acc[i][j] = __builtin_amdgcn_mfma_f32_16x16x32_bf16(af[i], bfr[j], acc[i][j], 0, 0, 0);
            if constexpr (MODE == 3) {
                bf16x8 bg[4];
#pragma unroll
                for (int j = 0; j < 4; ++j)
                    bg[j] = *(const bf16x8*)&Bs2[(wn + j * 16 + fr) * LDKT + kq];
#pragma unroll
                for (int i = 0; i < 4; ++i)
#pragma unroll
                    for (int j = 0; j < 4; ++j)
                        acc2[i][j] = __builtin_amdgcn_mfma_f32_16x16x32_bf16(af[i], bg[j], acc2[i][j], 0, 0, 0);
            }
        }
    }

    // epilogue: C[m][n], m = m0+wm+i*16+fq*4+r, n = n0+wn+j*16+fr
#pragma unroll
    for (int i = 0; i < 4; ++i) {
#pragma unroll
        for (int r = 0; r < 4; ++r) {
            const int m = m0 + wm + i * 16 + fq * 4 + r;
            if (m >= M) continue;
#pragma unroll
            for (int j = 0; j < 4; ++j) {
                const int n = n0 + wn + j * 16 + fr;
                float v;
                if constexpr (MODE == 4)
                    v = acc[i][j][r] + ((n < 256) ? bias1[n] : bias2[n - 256]);
                else
                    v = acc[i][j][r] + bias1[n];
                if constexpr (MODE == 0 || MODE == 4) {
                    out[(size_t)m * N + n] = (OUTT)v;
                } else if constexpr (MODE == 1) {
                    const int b = (m >= LQ) ? 1 : 0;
                    const int qi = m - b * LQ;
                    const int h = n >> 5;
                    const int c = n & 31;
                    out[((size_t)(b * NHD + h) * LQ + qi) * DHEAD + c] = (OUTT)v;
                } else if constexpr (MODE == 2) {
                    out[(size_t)m * N + n] =
                        (OUTT)(resid[(size_t)m * N + n] + ls[n] * v);
                } else {  // MODE 3 SwiGLU
                    const float sig = 1.0f / (1.0f + expf(-v));
                    const float v2 = acc2[i][j][r] + bias2[n];
                    out[(size_t)m * N + n] = (OUTT)(v * sig * v2);
                }
            }
        }
    }
}

// ---------------------------------------------------------------------------
// MSDeformAttn sampling v3: 2 tokens/block, 128 threads per token.
// Per token: 8 heads x (8 channel-lanes x 2 tap-halves). Each lane walks 32
// taps (half the chain of v2), partial sums combined with shfl_xor(8).
// proj: f32 (M,384): cols 0..255 = offsets, 256..383 = aw logits.
// value: bf16 (b,h,Lq,32).  out: bf16 (M,256).
// ---------------------------------------------------------------------------
__global__ __launch_bounds__(256)
void sample_kernel(const __hip_bfloat16* __restrict__ value,
                   const float* __restrict__ proj,
                   const float* __restrict__ ref,
                   __hip_bfloat16* __restrict__ out) {
    __shared__ float wsm[2][NHD][16];
    __shared__ int2  sTap[2][64][9];   // [token][pt*4+tap][head], slot 8 = pad

    const int tok0 = blockIdx.x * 2;   // MTOK even: both tokens always valid
    const int t = threadIdx.x;

    if (t < 16) {   // phase 1: softmax per (token, head)
        const int tl = t >> 3, h = t & 7;
        const int row = tok0 + tl;
        const float* lg = &proj[(size_t)row * 384 + 256 + h * 16];
        float v[16];
        float mx = -3.4e38f;
#pragma unroll
        for (int i = 0; i < 16; ++i) { v[i] = lg[i]; mx = fmaxf(mx, v[i]); }
        float s = 0.f;
#pragma unroll
        for (int i = 0; i < 16; ++i) { v[i] = expf(v[i] - mx); s += v[i]; }
        const float inv = 1.0f / s;
#pragma unroll
        for (int i = 0; i < 16; ++i) wsm[tl][h][i] = v[i] * inv;
    }
    __syncthreads();

    {   // phase 2: one (token, head, point) per thread -> 4 taps
        const int tl = t >> 7, hp = t & 127;
        const int row = tok0 + tl;
        const int h = hp >> 4, pt = hp & 15, lv = pt >> 2;
        const int Hs[4] = {100, 50, 25, 13};
        const int Ws[4] = {134, 67, 34, 17};
        const int stt[4] = {0, 13400, 16750, 17600};
        const int H = Hs[lv], W = Ws[lv];
        const float rx = ref[((size_t)row * 4 + lv) * 2 + 0];
        const float ry = ref[((size_t)row * 4 + lv) * 2 + 1];
        const float ox = proj[(size_t)row * 384 + h * 32 + pt * 2 + 0];
        const float oy = proj[(size_t)row * 384 + h * 32 + pt * 2 + 1];
        const float xf = rx * (float)W + ox - 0.5f;
        const float yf = ry * (float)H + oy - 0.5f;
        const float x0f = floorf(xf), y0f = floorf(yf);
        const float fx = xf - x0f, fy = yf - y0f;
        const int x0 = (int)x0f, y0 = (int)y0f;
        const float aw = wsm[tl][h][pt];
        const int b = (row >= LQ) ? 1 : 0;
        const int base = (b * NHD + h) * LQ + stt[lv];
#pragma unroll
        for (int tap = 0; tap < 4; ++tap) {
            const int dy = tap >> 1, dx = tap & 1;
            const int xi = x0 + dx, yi = y0 + dy;
            const bool valid = (xi >= 0) & (xi < W) & (yi >= 0) & (yi < H);
            const float wgt = (dx ? fx : 1.f - fx) * (dy ? fy : 1.f - fy) * aw;
            sTap[tl][pt * 4 + tap][h] = valid
                ? make_int2((base + yi * W + xi) * DHEAD, __float_as_int(wgt))
                : make_int2(0, 0);
        }
    }
    __syncthreads();

    // phase 3: gather-accumulate. 32 taps per lane, 4 channels each.
    const int tl = t >> 7, tg = t & 127;
    const int row = tok0 + tl;
    const int h = tg >> 4, sub = tg & 15;
    const int half = sub >> 3, c0 = (sub & 7) * 4;
    const char* vb = (const char*)value + (size_t)c0 * 2;
    float a0 = 0.f, a1 = 0.f, a2 = 0.f, a3 = 0.f;
    const int i0 = half * 32;
#pragma unroll 16
    for (int i = i0; i < i0 + 32; ++i) {
        const int2 tp = sTap[tl][i][h];
        const float w = __int_as_float(tp.y);
        const uint2 d = *(const uint2*)(vb + (size_t)tp.x * 2);
        a0 = fmaf(w, __int_as_float(d.x << 16), a0);
        a1 = fmaf(w, __int_as_float(d.x & 0xffff0000u), a1);
        a2 = fmaf(w, __int_as_float(d.y << 16), a2);
        a3 = fmaf(w, __int_as_float(d.y & 0xffff0000u), a3);
    }
    a0 += __shfl_xor(a0, 8, 64);
    a1 += __shfl_xor(a1, 8, 64);
    a2 += __shfl_xor(a2, 8, 64);
    a3 += __shfl_xor(a3, 8, 64);
    if (half == 0) {
        ushort4 o;
        o.x = bfpack(a0); o.y = bfpack(a1); o.z = bfpack(a2); o.w = bfpack(a3);
        *(ushort4*)&out[(size_t)row * 256 + h * 32 + c0] = o;
    }
}

// ---------------------------------------------------------------------------
// Workspace (bytes). MCb = 18.25 MB, MCf = 36.5 MB.
//   [0, MCb)              normed -> sampled (dead after Wo GEMM)
//   [MCb, 2MCb)           q -> n2
//   [2MCb, 3MCb)          value (dead after sampling)
//   [2MCb, 2MCb+MCf)      x_f  (over dead value + proj head)
//   [3MCb, 3MCb+54.7MB)   proj f32 (dead after sampling)
//   h_bf at [4MCb, ...) — beyond x_f end (R4 bug: 3MCb clobbered x_f).
//   1-chunk mode (needs 8MCb + 2MB): h = M x 1024 bf16, weights at 8MCb.
//   2-chunk fallback (R5-proven, ~111.5MB): h = chunk, weights at 109.5MB.
// ---------------------------------------------------------------------------
extern "C" void kernel_launch(void* const* d_in, const int* in_sizes, int n_in,
                              void* d_out, int out_size, void* d_ws, size_t ws_size,
                              hipStream_t stream) {
    const float* query      = (const float*)d_in[0];
    const float* query_pos  = (const float*)d_in[1];
    const float* ref        = (const float*)d_in[2];
    const float* norm_attn_w = (const float*)d_in[5];
    const float* Wv   = (const float*)d_in[6];
    const float* bv   = (const float*)d_in[7];
    const float* Woff = (const float*)d_in[8];
    const float* boff = (const float*)d_in[9];
    const float* Waw  = (const float*)d_in[10];
    const float* baw  = (const float*)d_in[11];
    const float* Wo   = (const float*)d_in[12];
    const float* bo   = (const float*)d_in[13];
    const float* ls_attn = (const float*)d_in[14];
    const float* norm_ffn_w = (const float*)d_in[15];
    const float* W1 = (const float*)d_in[16];
    const float* b1 = (const float*)d_in[17];
    const float* W2 = (const float*)d_in[18];
    const float* b2 = (const float*)d_in[19];
    const float* W3 = (const float*)d_in[20];
    const float* b3 = (const float*)d_in[21];
    const float* ls_ffn = (const float*)d_in[22];
    float* out = (float*)d_out;

    char* ws = (char*)d_ws;
    const size_t MCb = (size_t)MTOK * CDIM * 2;   // 18,248,704
    const size_t MCf = (size_t)MTOK * CDIM * 4;   // 36,497,408
    const size_t WBYTES = 2097152;                // bf16 weights, ~1.95 MB

    const bool one_chunk = ws_size >= 8 * MCb + WBYTES;

    __hip_bfloat16* normed_bf  = (__hip_bfloat16*)(ws);
    __hip_bfloat16* q_bf       = (__hip_bfloat16*)(ws + MCb);
    __hip_bfloat16* value_bf   = (__hip_bfloat16*)(ws + 2 * MCb);
    float*          proj_f     = (float*)(ws + 3 * MCb);            // M x 384
    __hip_bfloat16* sampled_bf = (__hip_bfloat16*)(ws);             // after normed/q dead
    float*          x_f        = (float*)(ws + 2 * MCb);            // after value dead
    __hip_bfloat16* n2_bf      = (__hip_bfloat16*)(ws + MCb);       // after q dead
    __hip_bfloat16* h_bf       = (__hip_bfloat16*)(ws + 4 * MCb);   // after x_f end
    __hip_bfloat16* wbf        = one_chunk
        ? (__hip_bfloat16*)(ws + 8 * MCb)
        : (__hip_bfloat16*)(ws + 3 * MCb + (size_t)MTOK * 384 * 4);

    __hip_bfloat16* Wv_bf    = wbf;
    __hip_bfloat16* Wproj_bf = wbf + 65536;    // Woff (256 rows) ++ Waw (128 rows)
    __hip_bfloat16* Wo_bf    = wbf + 163840;
    __hip_bfloat16* W1_bf    = wbf + 229376;
    __hip_bfloat16* W2_bf    = wbf + 491520;
    __hip_bfloat16* W3_bf    = wbf + 753664;

    // 0. all weight casts in one dispatch
    CastJobs cj;
    cj.src[0] = Wv;   cj.dst[0] = Wv_bf;            cj.n[0] = 65536;
    cj.src[1] = Woff; cj.dst[1] = Wproj_bf;         cj.n[1] = 65536;
    cj.src[2] = Waw;  cj.dst[2] = Wproj_bf + 65536; cj.n[2] = 32768;
    cj.src[3] = Wo;   cj.dst[3] = Wo_bf;            cj.n[3] = 65536;
    cj.src[4] = W1;   cj.dst[4] = W1_bf;            cj.n[4] = 262144;
    cj.src[5] = W2;   cj.dst[5] = W2_bf;            cj.n[5] = 262144;
    cj.src[6] = W3;   cj.dst[6] = W3_bf;            cj.n[6] = 262144;
    cast_all<<<dim3(1024, 7), 256, 0, stream>>>(cj);

    const int gx = (MTOK + GBM - 1) / GBM;   // 279
    const int gr = (MTOK + 3) / 4;           // 8911

    // 1. normed_bf, q_bf = normed + pos
    rmsnorm_kernel<true><<<gr, 256, 0, stream>>>(query, query_pos, norm_attn_w, normed_bf, q_bf);
    // 2. value = normed @ Wv^T + bv -> bf16 (b,h,q,c)
    mfma_gemm<1, 64, __hip_bfloat16><<<dim3(gx, 2), 256, 0, stream>>>(
        normed_bf, Wv_bf, bv, nullptr, nullptr, nullptr, nullptr, value_bf, MTOK, CDIM, CDIM);
    // 3. proj = q @ [Woff;Waw]^T + [boff;baw] -> f32 (M,384)
    mfma_gemm<4, 64, float><<<dim3(gx, 3), 256, 0, stream>>>(
        q_bf, Wproj_bf, boff, nullptr, baw, nullptr, nullptr, proj_f, MTOK, 384, CDIM);
    // 4. deformable sampling -> sampled_bf
    sample_kernel<<<MTOK / 2, 256, 0, stream>>>(value_bf, proj_f, ref, sampled_bf);
    // 5. x = query + ls_attn * (sampled @ Wo^T + bo) -> f32
    mfma_gemm<2, 64, float><<<dim3(gx, 2), 256, 0, stream>>>(
        sampled_bf, Wo_bf, bo, nullptr, nullptr, query, ls_attn, x_f, MTOK, CDIM, CDIM);
    // 6. n2 = rmsnorm(x) -> bf16
    rmsnorm_kernel<false><<<gr, 256, 0, stream>>>(x_f, nullptr, norm_ffn_w, n2_bf, nullptr);
    // 7/8. FFN: single pass if workspace allows, else 2 chunks of LQ rows
    const int chunk = one_chunk ? MTOK : LQ;
    for (int ms = 0; ms < MTOK; ms += chunk) {
        const int mc = chunk;
        const int gxc = (mc + GBM - 1) / GBM;
        mfma_gemm<3, 32, __hip_bfloat16><<<dim3(gxc, DFFN / GBN), 256, 0, stream>>>(
            n2_bf + (size_t)ms * CDIM, W1_bf, b1, W2_bf, b2, nullptr, nullptr,
            h_bf, mc, DFFN, CDIM);
        mfma_gemm<2, 64, float><<<dim3(gxc, 2), 256, 0, stream>>>(
            h_bf, W3_bf, b3, nullptr, nullptr, x_f + (size_t)ms * CDIM, ls_ffn,
            out + (size_t)ms * CDIM, mc, CDIM, DFFN);
    }
}

// Round 8
// 407.344 us; speedup vs baseline: 4.4705x; 1.1491x over previous
//
#include <hip/hip_runtime.h>
#include <hip/hip_bf16.h>
#include <cstddef>

// Problem constants (static shapes from the reference)
#define LQ   17821
#define BS   2
#define MTOK (BS * LQ)       // 35642 token rows
#define CDIM 256
#define NHD  8
#define DHEAD 32
#define DFFN 1024

typedef short bf16x4 __attribute__((ext_vector_type(4)));
typedef short bf16x8 __attribute__((ext_vector_type(8)));
typedef float f32x4  __attribute__((ext_vector_type(4)));
typedef float f32x2  __attribute__((ext_vector_type(2)));

// ---------------------------------------------------------------------------
// fp8 e4m3 (OCP) encode/decode helpers — HW path with SW fallback
// ---------------------------------------------------------------------------
__device__ __forceinline__ unsigned char fp8_enc(float f) {
#if __has_builtin(__builtin_amdgcn_cvt_pk_fp8_f32)
    return (unsigned char)(__builtin_amdgcn_cvt_pk_fp8_f32(f, f, 0, false) & 0xff);
#else
    unsigned s = (__float_as_uint(f) >> 31) << 7;
    float af = fabsf(f);
    if (af < 0.0078125f) return (unsigned char)s;   // flush tiny/subnormal
    af = fminf(af, 448.f);
    unsigned b = __float_as_uint(af);
    int e = (int)(b >> 23) - 127 + 7;
    unsigned m = (b >> 20) & 7;
    if (b & 0x80000) { m++; if (m == 8) { m = 0; e++; } }
    if (e < 1) return (unsigned char)s;
    if (e > 15) { e = 15; m = 6; }
    return (unsigned char)(s | ((unsigned)e << 3) | m);
#endif
}

__device__ __forceinline__ float fp8_dec_byte(unsigned x) {
    unsigned s = (x >> 7) & 1, e = (x >> 3) & 15, m = x & 7;
    float v = e ? __uint_as_float(((e + 120u) << 23) | (m << 20))
                : (float)m * 0.001953125f;
    return s ? -v : v;
}

// Decode 2 fp8 bytes (low pair HI=false, high pair HI=true) of a dword.
template <bool HI>
__device__ __forceinline__ f32x2 fp8_dec2(unsigned d) {
#if __has_builtin(__builtin_amdgcn_cvt_pk_f32_fp8)
    return __builtin_amdgcn_cvt_pk_f32_fp8(d, HI);
#else
    f32x2 r;
    r[0] = fp8_dec_byte((d >> (HI ? 16 : 0)) & 0xff);
    r[1] = fp8_dec_byte((d >> (HI ? 24 : 8)) & 0xff);
    return r;
#endif
}

// ---------------------------------------------------------------------------
// Batched fp32 -> bf16 weight cast (single dispatch)
// ---------------------------------------------------------------------------
struct CastJobs {
    const float* src[7];
    __hip_bfloat16* dst[7];
    int n[7];
};

__global__ __launch_bounds__(256)
void cast_all(CastJobs j) {
    const int seg = blockIdx.y;
    const int i = blockIdx.x * 256 + threadIdx.x;
    if (i < j.n[seg]) j.dst[seg][i] = (__hip_bfloat16)j.src[seg][i];
}

// ---------------------------------------------------------------------------
// RMSNorm, wave-per-token (64 lanes x float4 = 256 ch), 4 tokens/block.
// ---------------------------------------------------------------------------
__device__ __forceinline__ ushort bfpack(float f) {
    __hip_bfloat16 h = (__hip_bfloat16)f;
    return *(ushort*)&h;
}

template <bool ADD_POS>
__global__ __launch_bounds__(256)
void rmsnorm_kernel(const float* __restrict__ x, const float* __restrict__ pos,
                    const float* __restrict__ w,
                    __hip_bfloat16* __restrict__ outN, __hip_bfloat16* __restrict__ outQ) {
    const int tok = blockIdx.x * 4 + (threadIdx.x >> 6);
    if (tok >= MTOK) return;
    const int lane = threadIdx.x & 63;
    const size_t base = (size_t)tok * CDIM + lane * 4;
    const float4 v = *(const float4*)&x[base];
    float ss = v.x * v.x + v.y * v.y + v.z * v.z + v.w * v.w;
#pragma unroll
    for (int m = 1; m < 64; m <<= 1) ss += __shfl_xor(ss, m, 64);
    const float r = rsqrtf(ss * (1.0f / CDIM) + 1e-6f);
    const float4 wv = *(const float4*)&w[lane * 4];
    const float n0 = v.x * r * wv.x, n1 = v.y * r * wv.y;
    const float n2 = v.z * r * wv.z, n3 = v.w * r * wv.w;
    ushort4 o;
    o.x = bfpack(n0); o.y = bfpack(n1); o.z = bfpack(n2); o.w = bfpack(n3);
    *(ushort4*)&outN[base] = o;
    if (ADD_POS) {
        const float4 p = *(const float4*)&pos[base];
        ushort4 q;
        q.x = bfpack(n0 + p.x); q.y = bfpack(n1 + p.y);
        q.z = bfpack(n2 + p.z); q.w = bfpack(n3 + p.w);
        *(ushort4*)&outQ[base] = q;
    }
}

// ---------------------------------------------------------------------------
// bf16 MFMA GEMM: C[M,N] = A[M,K] @ W[N,K]^T (+ epilogues), fp32 accumulate.
// 128x128 block tile, templated BK (32 or 64), 4 waves (2x2), each wave 4x4
// of 16x16x32 MFMA per 32-wide k-step. Register-prefetch pipeline.
// MODE 0: out = acc + bias1
// MODE 1: value layout write (b, h, q, c), fp8 e4m3 (OUTT = unsigned char)
// MODE 2: out = resid + ls * (acc + bias1)
// MODE 3: out = silu(acc1+bias1) * (acc2+bias2)   (dual weights, BK=32)
// MODE 4: out = acc + concat(bias1[0:256], bias2[0:128])[n]   (proj N=384)
// ---------------------------------------------------------------------------
#define GBM 128
#define GBN 128

template <int MODE, int BKT, typename OUTT>
__global__ __launch_bounds__(256, 2)
void mfma_gemm(const __hip_bfloat16* __restrict__ A,
               const __hip_bfloat16* __restrict__ B1, const float* __restrict__ bias1,
               const __hip_bfloat16* __restrict__ B2, const float* __restrict__ bias2,
               const float* __restrict__ resid, const float* __restrict__ ls,
               OUTT* __restrict__ out, int M, int N, int K) {
    constexpr int LDKT = BKT + 8;        // +16B pad: 2-way bank alias (free)
    constexpr int CH = BKT / 16;         // uint4 staging chunks per thread per matrix
    constexpr int CPR = BKT / 8;         // 8-elem chunks per row

    __shared__ short As[GBM * LDKT];
    __shared__ short Bs[GBN * LDKT];
    __shared__ short Bs2[(MODE == 3) ? GBN * LDKT : 1];

    const int tid = threadIdx.x;
    const int m0 = blockIdx.x * GBM;
    const int n0 = blockIdx.y * GBN;
    const int wave = tid >> 6;
    const int lane = tid & 63;
    const int wm = (wave >> 1) * 64;
    const int wn = (wave & 1) * 64;
    const int fr = lane & 15;   // col of C
    const int fq = lane >> 4;   // quad: k = fq*8+j ; C row = fq*4+r

    f32x4 acc[4][4] = {};
    f32x4 acc2[(MODE == 3) ? 4 : 1][(MODE == 3) ? 4 : 1] = {};

    // staging map: chunk g = tid + cc*256; row = g / CPR, kc = (g % CPR) * 8
    int srow[CH], skc[CH];
#pragma unroll
    for (int cc = 0; cc < CH; ++cc) {
        const int g = tid + cc * 256;
        srow[cc] = g / CPR;
        skc[cc] = (g % CPR) * 8;
    }
    const uint4 zero4 = make_uint4(0, 0, 0, 0);

    uint4 ra[CH], rb[CH], rc[(MODE == 3) ? CH : 1];
#pragma unroll
    for (int cc = 0; cc < CH; ++cc) {
        const int gm = m0 + srow[cc];
        ra[cc] = (gm < M) ? *(const uint4*)&A[(size_t)gm * K + skc[cc]] : zero4;
        rb[cc] = *(const uint4*)&B1[(size_t)(n0 + srow[cc]) * K + skc[cc]];
        if constexpr (MODE == 3)
            rc[cc] = *(const uint4*)&B2[(size_t)(n0 + srow[cc]) * K + skc[cc]];
    }

    for (int k0 = 0; k0 < K; k0 += BKT) {
        __syncthreads();   // prev tile's LDS reads done
#pragma unroll
        for (int cc = 0; cc < CH; ++cc) {
            short* pa = &As[srow[cc] * LDKT + skc[cc]];
            short* pb = &Bs[srow[cc] * LDKT + skc[cc]];
            union { uint4 u; bf16x4 h[2]; } cv;
            cv.u = ra[cc]; ((bf16x4*)pa)[0] = cv.h[0]; ((bf16x4*)pa)[1] = cv.h[1];
            cv.u = rb[cc]; ((bf16x4*)pb)[0] = cv.h[0]; ((bf16x4*)pb)[1] = cv.h[1];
            if constexpr (MODE == 3) {
                short* pc = &Bs2[srow[cc] * LDKT + skc[cc]];
                cv.u = rc[cc]; ((bf16x4*)pc)[0] = cv.h[0]; ((bf16x4*)pc)[1] = cv.h[1];
            }
        }
        __syncthreads();

        if (k0 + BKT < K) {   // issue next-tile loads; latency overlaps MFMAs below
            const int kn = k0 + BKT;
#pragma unroll
            for (int cc = 0; cc < CH; ++cc) {
                const int gm = m0 + srow[cc];
                ra[cc] = (gm < M) ? *(const uint4*)&A[(size_t)gm * K + kn + skc[cc]] : zero4;
                rb[cc] = *(const uint4*)&B1[(size_t)(n0 + srow[cc]) * K + kn + skc[cc]];
                if constexpr (MODE == 3)
                    rc[cc] = *(const uint4*)&B2[(size_t)(n0 + srow[cc]) * K + kn + skc[cc]];
            }
        }

#pragma unroll
        for (int kk = 0; kk < BKT; kk += 32) {
            const int kq = kk + fq * 8;
            bf16x8 af[4], bfr[4];
#pragma unroll
            for (int i = 0; i < 4; ++i)
                af[i] = *(const bf16x8*)&As[(wm + i * 16 + fr) * LDKT + kq];
#pragma unroll
            for (int j = 0; j < 4; ++j)
                bfr[j] = *(const bf16x8*)&Bs[(wn + j * 16 + fr) * LDKT + kq];
#pragma unroll
            for (int i = 0; i < 4; ++i)
#pragma unroll
                for (int j = 0; j < 4; ++j)
                    acc[i][j] = __builtin_amdgcn_mfma_f32_16x16x32_bf16(af[i], bfr[j], acc[i][j], 0, 0, 0);
            if constexpr (MODE == 3) {
                bf16x8 bg[4];
#pragma unroll
                for (int j = 0; j < 4; ++j)
                    bg[j] = *(const bf16x8*)&Bs2[(wn + j * 16 + fr) * LDKT + kq];
#pragma unroll
                for (int i = 0; i < 4; ++i)
#pragma unroll
                    for (int j = 0; j < 4; ++j)
                        acc2[i][j] = __builtin_amdgcn_mfma_f32_16x16x32_bf16(af[i], bg[j], acc2[i][j], 0, 0, 0);
            }
        }
    }

    // epilogue: C[m][n], m = m0+wm+i*16+fq*4+r, n = n0+wn+j*16+fr
#pragma unroll
    for (int i = 0; i < 4; ++i) {
#pragma unroll
        for (int r = 0; r < 4; ++r) {
            const int m = m0 + wm + i * 16 + fq * 4 + r;
            if (m >= M) continue;
#pragma unroll
            for (int j = 0; j < 4; ++j) {
                const int n = n0 + wn + j * 16 + fr;
                float v;
                if constexpr (MODE == 4)
                    v = acc[i][j][r] + ((n < 256) ? bias1[n] : bias2[n - 256]);
                else
                    v = acc[i][j][r] + bias1[n];
                if constexpr (MODE == 0 || MODE == 4) {
                    out[(size_t)m * N + n] = (OUTT)v;
                } else if constexpr (MODE == 1) {
                    const int b = (m >= LQ) ? 1 : 0;
                    const int qi = m - b * LQ;
                    const int h = n >> 5;
                    const int c = n & 31;
                    ((unsigned char*)out)[((size_t)(b * NHD + h) * LQ + qi) * DHEAD + c] = fp8_enc(v);
                } else if constexpr (MODE == 2) {
                    out[(size_t)m * N + n] =
                        (OUTT)(resid[(size_t)m * N + n] + ls[n] * v);
                } else {  // MODE 3 SwiGLU
                    const float sig = 1.0f / (1.0f + expf(-v));
                    const float v2 = acc2[i][j][r] + bias2[n];
                    out[(size_t)m * N + n] = (OUTT)(v * sig * v2);
                }
            }
        }
    }
}

// ---------------------------------------------------------------------------
// MSDeformAttn sampling v4 (= proven v2 structure + fp8 value + bf16 proj).
// 4 tokens/block (one wave each).
// Phase 1 (32 thr):  softmax of 16 bf16 logits per (token, head) -> LDS
// Phase 2 (256 thr x2): tap (byte-idx, weight) int2 -> LDS [64][9] (pad)
// Phase 3: lane = (h, 4 channels); dword gather (4 fp8) + cvt + 4 FMA per tap.
// proj: bf16 (M,384): cols 0..255 = offsets, 256..383 = aw logits.
// value: fp8 e4m3 (b,h,Lq,32).  out: bf16 (M,256).
// ---------------------------------------------------------------------------
__global__ __launch_bounds__(256)
void sample_kernel(const unsigned char* __restrict__ value,
                   const ushort* __restrict__ proj,
                   const float* __restrict__ ref,
                   __hip_bfloat16* __restrict__ out) {
    __shared__ float wsm[4][NHD][16];
    __shared__ int2  sTap[4][64][9];   // [token][pt*4+tap][head], slot 8 = pad

    const int tok0 = blockIdx.x * 4;
    const int t = threadIdx.x;

    if (t < 32) {
        const int tl = t >> 3, h = t & 7;
        const int row = tok0 + tl;
        if (row < MTOK) {
            const ushort* lg = &proj[(size_t)row * 384 + 256 + h * 16];
            float v[16];
            float mx = -3.4e38f;
#pragma unroll
            for (int i = 0; i < 16; ++i) {
                v[i] = __uint_as_float((unsigned)lg[i] << 16);
                mx = fmaxf(mx, v[i]);
            }
            float s = 0.f;
#pragma unroll
            for (int i = 0; i < 16; ++i) { v[i] = expf(v[i] - mx); s += v[i]; }
            const float inv = 1.0f / s;
#pragma unroll
            for (int i = 0; i < 16; ++i) wsm[tl][h][i] = v[i] * inv;
        }
    }
    __syncthreads();

#pragma unroll
    for (int e = t; e < 512; e += 256) {
        const int tl = e >> 7, hp = e & 127;
        const int row = tok0 + tl;
        if (row < MTOK) {
            const int h = hp >> 4, pt = hp & 15, lv = pt >> 2;
            const int Hs[4] = {100, 50, 25, 13};
            const int Ws[4] = {134, 67, 34, 17};
            const int stt[4] = {0, 13400, 16750, 17600};
            const int H = Hs[lv], W = Ws[lv];
            const float rx = ref[((size_t)row * 4 + lv) * 2 + 0];
            const float ry = ref[((size_t)row * 4 + lv) * 2 + 1];
            const float ox = __uint_as_float((unsigned)proj[(size_t)row * 384 + h * 32 + pt * 2 + 0] << 16);
            const float oy = __uint_as_float((unsigned)proj[(size_t)row * 384 + h * 32 + pt * 2 + 1] << 16);
            const float xf = rx * (float)W + ox - 0.5f;
            const float yf = ry * (float)H + oy - 0.5f;
            const float x0f = floorf(xf), y0f = floorf(yf);
            const float fx = xf - x0f, fy = yf - y0f;
            const int x0 = (int)x0f, y0 = (int)y0f;
            const float aw = wsm[tl][h][pt];
            const int b = (row >= LQ) ? 1 : 0;
            const int base = (b * NHD + h) * LQ + stt[lv];
#pragma unroll
            for (int tap = 0; tap < 4; ++tap) {
                const int dy = tap >> 1, dx = tap & 1;
                const int xi = x0 + dx, yi = y0 + dy;
                const bool valid = (xi >= 0) & (xi < W) & (yi >= 0) & (yi < H);
                const float wgt = (dx ? fx : 1.f - fx) * (dy ? fy : 1.f - fy) * aw;
                sTap[tl][pt * 4 + tap][h] = valid
                    ? make_int2((base + yi * W + xi) * DHEAD, __float_as_int(wgt))
                    : make_int2(0, 0);
            }
        }
    }
    __syncthreads();

    const int tl = t >> 6, lane = t & 63;
    const int row = tok0 + tl;
    if (row >= MTOK) return;
    const int h = lane >> 3, c0 = (lane & 7) * 4;
    const unsigned char* vb = value + c0;
    float a0 = 0.f, a1 = 0.f, a2 = 0.f, a3 = 0.f;
#pragma unroll 8
    for (int i = 0; i < 64; ++i) {
        const int2 tp = sTap[tl][i][h];
        const float w = __int_as_float(tp.y);
        const unsigned d = *(const unsigned*)(vb + (size_t)tp.x);
        const f32x2 lo = fp8_dec2<false>(d);
        const f32x2 hi = fp8_dec2<true>(d);
        a0 = fmaf(w, lo[0], a0);
        a1 = fmaf(w, lo[1], a1);
        a2 = fmaf(w, hi[0], a2);
        a3 = fmaf(w, hi[1], a3);
    }
    ushort4 o;
    o.x = bfpack(a0); o.y = bfpack(a1); o.z = bfpack(a2); o.w = bfpack(a3);
    *(ushort4*)&out[(size_t)row * 256 + h * 32 + c0] = o;
}

// ---------------------------------------------------------------------------
// Workspace (bytes). MCb = 18.25 MB, MCf = 36.5 MB.
//   [0, MCb)              normed -> sampled (dead after Wo GEMM)
//   [MCb, 2MCb)           q -> n2
//   [2MCb, 2MCb+9.1MB)    value fp8 (dead after sampling)
//   [2MCb, 2MCb+MCf)      x_f  (over dead value + proj head, written step 5)
//   [3MCb, 3MCb+27.4MB)   proj bf16 (dead after sampling)
//   h_bf at [4MCb, ...) — beyond x_f end (R4 bug: 3MCb clobbered x_f).
//   1-chunk mode (needs 8MCb + 2MB): h = M x 1024 bf16, weights at 8MCb.
//   2-chunk fallback: h = LQ-chunk at 4MCb, weights at 3MCb + 54.7MB.
// ---------------------------------------------------------------------------
extern "C" void kernel_launch(void* const* d_in, const int* in_sizes, int n_in,
                              void* d_out, int out_size, void* d_ws, size_t ws_size,
                              hipStream_t stream) {
    const float* query      = (const float*)d_in[0];
    const float* query_pos  = (const float*)d_in[1];
    const float* ref        = (const float*)d_in[2];
    const float* norm_attn_w = (const float*)d_in[5];
    const float* Wv   = (const float*)d_in[6];
    const float* bv   = (const float*)d_in[7];
    const float* Woff = (const float*)d_in[8];
    const float* boff = (const float*)d_in[9];
    const float* Waw  = (const float*)d_in[10];
    const float* baw  = (const float*)d_in[11];
    const float* Wo   = (const float*)d_in[12];
    const float* bo   = (const float*)d_in[13];
    const float* ls_attn = (const float*)d_in[14];
    const float* norm_ffn_w = (const float*)d_in[15];
    const float* W1 = (const float*)d_in[16];
    const float* b1 = (const float*)d_in[17];
    const float* W2 = (const float*)d_in[18];
    const float* b2 = (const float*)d_in[19];
    const float* W3 = (const float*)d_in[20];
    const float* b3 = (const float*)d_in[21];
    const float* ls_ffn = (const float*)d_in[22];
    float* out = (float*)d_out;

    char* ws = (char*)d_ws;
    const size_t MCb = (size_t)MTOK * CDIM * 2;   // 18,248,704
    const size_t MCf = (size_t)MTOK * CDIM * 4;   // 36,497,408
    const size_t WBYTES = 2097152;                // bf16 weights, ~1.95 MB

    const bool one_chunk = ws_size >= 8 * MCb + WBYTES;

    __hip_bfloat16* normed_bf  = (__hip_bfloat16*)(ws);
    __hip_bfloat16* q_bf       = (__hip_bfloat16*)(ws + MCb);
    unsigned char*  value_u8   = (unsigned char*)(ws + 2 * MCb);
    __hip_bfloat16* proj_bf    = (__hip_bfloat16*)(ws + 3 * MCb);   // M x 384 bf16
    __hip_bfloat16* sampled_bf = (__hip_bfloat16*)(ws);             // after normed/q dead
    float*          x_f        = (float*)(ws + 2 * MCb);            // after value dead
    __hip_bfloat16* n2_bf      = (__hip_bfloat16*)(ws + MCb);       // after q dead
    __hip_bfloat16* h_bf       = (__hip_bfloat16*)(ws + 4 * MCb);   // after x_f end
    __hip_bfloat16* wbf        = one_chunk
        ? (__hip_bfloat16*)(ws + 8 * MCb)
        : (__hip_bfloat16*)(ws + 3 * MCb + (size_t)MTOK * 384 * 4);

    __hip_bfloat16* Wv_bf    = wbf;
    __hip_bfloat16* Wproj_bf = wbf + 65536;    // Woff (256 rows) ++ Waw (128 rows)
    __hip_bfloat16* Wo_bf    = wbf + 163840;
    __hip_bfloat16* W1_bf    = wbf + 229376;
    __hip_bfloat16* W2_bf    = wbf + 491520;
    __hip_bfloat16* W3_bf    = wbf + 753664;

    // 0. all weight casts in one dispatch
    CastJobs cj;
    cj.src[0] = Wv;   cj.dst[0] = Wv_bf;            cj.n[0] = 65536;
    cj.src[1] = Woff; cj.dst[1] = Wproj_bf;         cj.n[1] = 65536;
    cj.src[2] = Waw;  cj.dst[2] = Wproj_bf + 65536; cj.n[2] = 32768;
    cj.src[3] = Wo;   cj.dst[3] = Wo_bf;            cj.n[3] = 65536;
    cj.src[4] = W1;   cj.dst[4] = W1_bf;            cj.n[4] = 262144;
    cj.src[5] = W2;   cj.dst[5] = W2_bf;            cj.n[5] = 262144;
    cj.src[6] = W3;   cj.dst[6] = W3_bf;            cj.n[6] = 262144;
    cast_all<<<dim3(1024, 7), 256, 0, stream>>>(cj);

    const int gx = (MTOK + GBM - 1) / GBM;   // 279
    const int gr = (MTOK + 3) / 4;           // 8911

    // 1. normed_bf, q_bf = normed + pos
    rmsnorm_kernel<true><<<gr, 256, 0, stream>>>(query, query_pos, norm_attn_w, normed_bf, q_bf);
    // 2. value = normed @ Wv^T + bv -> fp8 (b,h,q,c)
    mfma_gemm<1, 64, unsigned char><<<dim3(gx, 2), 256, 0, stream>>>(
        normed_bf, Wv_bf, bv, nullptr, nullptr, nullptr, nullptr, value_u8, MTOK, CDIM, CDIM);
    // 3. proj = q @ [Woff;Waw]^T + [boff;baw] -> bf16 (M,384)
    mfma_gemm<4, 64, __hip_bfloat16><<<dim3(gx, 3), 256, 0, stream>>>(
        q_bf, Wproj_bf, boff, nullptr, baw, nullptr, nullptr, proj_bf, MTOK, 384, CDIM);
    // 4. deformable sampling -> sampled_bf
    sample_kernel<<<gr, 256, 0, stream>>>(value_u8, (const ushort*)proj_bf, ref, sampled_bf);
    // 5. x = query + ls_attn * (sampled @ Wo^T + bo) -> f32
    mfma_gemm<2, 64, float><<<dim3(gx, 2), 256, 0, stream>>>(
        sampled_bf, Wo_bf, bo, nullptr, nullptr, query, ls_attn, x_f, MTOK, CDIM, CDIM);
    // 6. n2 = rmsnorm(x) -> bf16
    rmsnorm_kernel<false><<<gr, 256, 0, stream>>>(x_f, nullptr, norm_ffn_w, n2_bf, nullptr);
    // 7/8. FFN: single pass if workspace allows, else 2 chunks of LQ rows
    const int chunk = one_chunk ? MTOK : LQ;
    for (int ms = 0; ms < MTOK; ms += chunk) {
        const int mc = chunk;
        const int gxc = (mc + GBM - 1) / GBM;
        mfma_gemm<3, 32, __hip_bfloat16><<<dim3(gxc, DFFN / GBN), 256, 0, stream>>>(
            n2_bf + (size_t)ms * CDIM, W1_bf, b1, W2_bf, b2, nullptr, nullptr,
            h_bf, mc, DFFN, CDIM);
        mfma_gemm<2, 64, float><<<dim3(gxc, 2), 256, 0, stream>>>(
            h_bf, W3_bf, b3, nullptr, nullptr, x_f + (size_t)ms * CDIM, ls_ffn,
            out + (size_t)ms * CDIM, mc, CDIM, DFFN);
    }
}

// Round 9
// 407.247 us; speedup vs baseline: 4.4716x; 1.0002x over previous
//
#include <hip/hip_runtime.h>
#include <hip/hip_bf16.h>
#include <cstddef>

// Problem constants (static shapes from the reference)
#define LQ   17821
#define BS   2
#define MTOK (BS * LQ)       // 35642 token rows
#define CDIM 256
#define NHD  8
#define DHEAD 32
#define DFFN 1024

typedef short bf16x4 __attribute__((ext_vector_type(4)));
typedef short bf16x8 __attribute__((ext_vector_type(8)));
typedef float f32x4  __attribute__((ext_vector_type(4)));
typedef float f32x2  __attribute__((ext_vector_type(2)));

// ---------------------------------------------------------------------------
// fp8 e4m3 (OCP) encode/decode helpers — HW path with SW fallback
// ---------------------------------------------------------------------------
__device__ __forceinline__ unsigned char fp8_enc(float f) {
#if __has_builtin(__builtin_amdgcn_cvt_pk_fp8_f32)
    return (unsigned char)(__builtin_amdgcn_cvt_pk_fp8_f32(f, f, 0, false) & 0xff);
#else
    unsigned s = (__float_as_uint(f) >> 31) << 7;
    float af = fabsf(f);
    if (af < 0.0078125f) return (unsigned char)s;   // flush tiny/subnormal
    af = fminf(af, 448.f);
    unsigned b = __float_as_uint(af);
    int e = (int)(b >> 23) - 127 + 7;
    unsigned m = (b >> 20) & 7;
    if (b & 0x80000) { m++; if (m == 8) { m = 0; e++; } }
    if (e < 1) return (unsigned char)s;
    if (e > 15) { e = 15; m = 6; }
    return (unsigned char)(s | ((unsigned)e << 3) | m);
#endif
}

__device__ __forceinline__ float fp8_dec_byte(unsigned x) {
    unsigned s = (x >> 7) & 1, e = (x >> 3) & 15, m = x & 7;
    float v = e ? __uint_as_float(((e + 120u) << 23) | (m << 20))
                : (float)m * 0.001953125f;
    return s ? -v : v;
}

// Decode 2 fp8 bytes (low pair HI=false, high pair HI=true) of a dword.
template <bool HI>
__device__ __forceinline__ f32x2 fp8_dec2(unsigned d) {
#if __has_builtin(__builtin_amdgcn_cvt_pk_f32_fp8)
    return __builtin_amdgcn_cvt_pk_f32_fp8(d, HI);
#else
    f32x2 r;
    r[0] = fp8_dec_byte((d >> (HI ? 16 : 0)) & 0xff);
    r[1] = fp8_dec_byte((d >> (HI ? 24 : 8)) & 0xff);
    return r;
#endif
}

// ---------------------------------------------------------------------------
// Batched fp32 -> bf16 weight cast; optional per-column scale (norm folding)
// ---------------------------------------------------------------------------
struct CastJobs {
    const float* src[7];
    __hip_bfloat16* dst[7];
    const float* colw[7];   // if non-null: dst = src * colw[i & 255]
    int n[7];
};

__global__ __launch_bounds__(256)
void cast_all(CastJobs j) {
    const int seg = blockIdx.y;
    const int i = blockIdx.x * 256 + threadIdx.x;
    if (i < j.n[seg]) {
        float v = j.src[seg][i];
        if (j.colw[seg]) v *= j.colw[seg][i & 255];
        j.dst[seg][i] = (__hip_bfloat16)v;
    }
}

// ---------------------------------------------------------------------------
// RMSNorm, wave-per-token (64 lanes x float4 = 256 ch), 4 tokens/block.
// ---------------------------------------------------------------------------
__device__ __forceinline__ ushort bfpack(float f) {
    __hip_bfloat16 h = (__hip_bfloat16)f;
    return *(ushort*)&h;
}

template <bool ADD_POS>
__global__ __launch_bounds__(256)
void rmsnorm_kernel(const float* __restrict__ x, const float* __restrict__ pos,
                    const float* __restrict__ w,
                    __hip_bfloat16* __restrict__ outN, __hip_bfloat16* __restrict__ outQ) {
    const int tok = blockIdx.x * 4 + (threadIdx.x >> 6);
    if (tok >= MTOK) return;
    const int lane = threadIdx.x & 63;
    const size_t base = (size_t)tok * CDIM + lane * 4;
    const float4 v = *(const float4*)&x[base];
    float ss = v.x * v.x + v.y * v.y + v.z * v.z + v.w * v.w;
#pragma unroll
    for (int m = 1; m < 64; m <<= 1) ss += __shfl_xor(ss, m, 64);
    const float r = rsqrtf(ss * (1.0f / CDIM) + 1e-6f);
    const float4 wv = *(const float4*)&w[lane * 4];
    const float n0 = v.x * r * wv.x, n1 = v.y * r * wv.y;
    const float n2 = v.z * r * wv.z, n3 = v.w * r * wv.w;
    ushort4 o;
    o.x = bfpack(n0); o.y = bfpack(n1); o.z = bfpack(n2); o.w = bfpack(n3);
    *(ushort4*)&outN[base] = o;
    if (ADD_POS) {
        const float4 p = *(const float4*)&pos[base];
        ushort4 q;
        q.x = bfpack(n0 + p.x); q.y = bfpack(n1 + p.y);
        q.z = bfpack(n2 + p.z); q.w = bfpack(n3 + p.w);
        *(ushort4*)&outQ[base] = q;
    }
}

// ---------------------------------------------------------------------------
// Row RMS scale only: r[m] = rsqrt(mean(x^2)+eps), x bf16. 4 tokens/block.
// ---------------------------------------------------------------------------
__global__ __launch_bounds__(256)
void rowrms_kernel(const __hip_bfloat16* __restrict__ x, float* __restrict__ r) {
    const int tok = blockIdx.x * 4 + (threadIdx.x >> 6);
    if (tok >= MTOK) return;
    const int lane = threadIdx.x & 63;
    const ushort4 u = *(const ushort4*)&x[(size_t)tok * CDIM + lane * 4];
    const float v0 = __uint_as_float((unsigned)u.x << 16);
    const float v1 = __uint_as_float((unsigned)u.y << 16);
    const float v2 = __uint_as_float((unsigned)u.z << 16);
    const float v3 = __uint_as_float((unsigned)u.w << 16);
    float ss = v0 * v0 + v1 * v1 + v2 * v2 + v3 * v3;
#pragma unroll
    for (int m = 1; m < 64; m <<= 1) ss += __shfl_xor(ss, m, 64);
    if (lane == 0) r[tok] = rsqrtf(ss * (1.0f / CDIM) + 1e-6f);
}

// ---------------------------------------------------------------------------
// bf16 MFMA GEMM: C[M,N] = A[M,K] @ W[N,K]^T (+ epilogues), fp32 accumulate.
// 128x128 block tile, templated BK, 4 waves (2x2), wave = 4x4 of 16x16x32.
// MODE 0: out = acc + bias1
// MODE 1: value layout write (b, h, q, c), fp8 e4m3
// MODE 2: out = resid_f32 + ls * (acc + bias1)          (OUTT selects store)
// MODE 4: out = acc + concat(bias1[0:256], bias2[0:128])[n]   (proj N=384)
// MODE 5: out = resid_bf16 + ls * (acc + bias1), f32 out
// ---------------------------------------------------------------------------
#define GBM 128
#define GBN 128

template <int MODE, int BKT, typename OUTT>
__global__ __launch_bounds__(256, 2)
void mfma_gemm(const __hip_bfloat16* __restrict__ A,
               const __hip_bfloat16* __restrict__ B1, const float* __restrict__ bias1,
               const float* __restrict__ bias2,
               const float* __restrict__ resid, const __hip_bfloat16* __restrict__ residb,
               const float* __restrict__ ls,
               OUTT* __restrict__ out, int M, int N, int K) {
    constexpr int LDKT = BKT + 8;        // +16B pad: 2-way bank alias (free)
    constexpr int CH = BKT / 16;         // uint4 staging chunks per thread per matrix
    constexpr int CPR = BKT / 8;         // 8-elem chunks per row

    __shared__ short As[GBM * LDKT];
    __shared__ short Bs[GBN * LDKT];

    const int tid = threadIdx.x;
    const int m0 = blockIdx.x * GBM;
    const int n0 = blockIdx.y * GBN;
    const int wave = tid >> 6;
    const int lane = tid & 63;
    const int wm = (wave >> 1) * 64;
    const int wn = (wave & 1) * 64;
    const int fr = lane & 15;   // col of C
    const int fq = lane >> 4;   // quad: k = fq*8+j ; C row = fq*4+r

    f32x4 acc[4][4] = {};

    int srow[CH], skc[CH];
#pragma unroll
    for (int cc = 0; cc < CH; ++cc) {
        const int g = tid + cc * 256;
        srow[cc] = g / CPR;
        skc[cc] = (g % CPR) * 8;
    }
    const uint4 zero4 = make_uint4(0, 0, 0, 0);

    uint4 ra[CH], rb[CH];
#pragma unroll
    for (int cc = 0; cc < CH; ++cc) {
        const int gm = m0 + srow[cc];
        ra[cc] = (gm < M) ? *(const uint4*)&A[(size_t)gm * K + skc[cc]] : zero4;
        rb[cc] = *(const uint4*)&B1[(size_t)(n0 + srow[cc]) * K + skc[cc]];
    }

    for (int k0 = 0; k0 < K; k0 += BKT) {
        __syncthreads();
#pragma unroll
        for (int cc = 0; cc < CH; ++cc) {
            short* pa = &As[srow[cc] * LDKT + skc[cc]];
            short* pb = &Bs[srow[cc] * LDKT + skc[cc]];
            union { uint4 u; bf16x4 h[2]; } cv;
            cv.u = ra[cc]; ((bf16x4*)pa)[0] = cv.h[0]; ((bf16x4*)pa)[1] = cv.h[1];
            cv.u = rb[cc]; ((bf16x4*)pb)[0] = cv.h[0]; ((bf16x4*)pb)[1] = cv.h[1];
        }
        __syncthreads();

        if (k0 + BKT < K) {
            const int kn = k0 + BKT;
#pragma unroll
            for (int cc = 0; cc < CH; ++cc) {
                const int gm = m0 + srow[cc];
                ra[cc] = (gm < M) ? *(const uint4*)&A[(size_t)gm * K + kn + skc[cc]] : zero4;
                rb[cc] = *(const uint4*)&B1[(size_t)(n0 + srow[cc]) * K + kn + skc[cc]];
            }
        }

#pragma unroll
        for (int kk = 0; kk < BKT; kk += 32) {
            const int kq = kk + fq * 8;
            bf16x8 af[4], bfr[4];
#pragma unroll
            for (int i = 0; i < 4; ++i)
                af[i] = *(const bf16x8*)&As[(wm + i * 16 + fr) * LDKT + kq];
#pragma unroll
            for (int j = 0; j < 4; ++j)
                bfr[j] = *(const bf16x8*)&Bs[(wn + j * 16 + fr) * LDKT + kq];
#pragma unroll
            for (int i = 0; i < 4; ++i)
#pragma unroll
                for (int j = 0; j < 4; ++j)
                    acc[i][j] = __builtin_amdgcn_mfma_f32_16x16x32_bf16(af[i], bfr[j], acc[i][j], 0, 0, 0);
        }
    }

#pragma unroll
    for (int i = 0; i < 4; ++i) {
#pragma unroll
        for (int r = 0; r < 4; ++r) {
            const int m = m0 + wm + i * 16 + fq * 4 + r;
            if (m >= M) continue;
#pragma unroll
            for (int j = 0; j < 4; ++j) {
                const int n = n0 + wn + j * 16 + fr;
                float v;
                if constexpr (MODE == 4)
                    v = acc[i][j][r] + ((n < 256) ? bias1[n] : bias2[n - 256]);
                else
                    v = acc[i][j][r] + bias1[n];
                if constexpr (MODE == 0 || MODE == 4) {
                    out[(size_t)m * N + n] = (OUTT)v;
                } else if constexpr (MODE == 1) {
                    const int b = (m >= LQ) ? 1 : 0;
                    const int qi = m - b * LQ;
                    const int h = n >> 5;
                    const int c = n & 31;
                    ((unsigned char*)out)[((size_t)(b * NHD + h) * LQ + qi) * DHEAD + c] = fp8_enc(v);
                } else if constexpr (MODE == 2) {
                    out[(size_t)m * N + n] =
                        (OUTT)(resid[(size_t)m * N + n] + ls[n] * v);
                } else {  // MODE 5: bf16 residual, f32 out
                    const float rx = __uint_as_float(
                        (unsigned)(*(const ushort*)&residb[(size_t)m * N + n]) << 16);
                    out[(size_t)m * N + n] = (OUTT)(rx + ls[n] * v);
                }
            }
        }
    }
}

// ---------------------------------------------------------------------------
// SwiGLU dual GEMM: h = silu(r[m]*(x@W1'^T)+b1) * (r[m]*(x@W2'^T)+b2)
// 128x64 block tile (small acc -> 3 waves/SIMD), BK=32, 4 waves 2x2,
// wave tile 64x32 per matrix (acc 32+32 f32). W1',W2' have norm w folded.
// ---------------------------------------------------------------------------
__global__ __launch_bounds__(256, 3)
void mfma_swiglu(const __hip_bfloat16* __restrict__ A,
                 const __hip_bfloat16* __restrict__ B1, const float* __restrict__ bias1,
                 const __hip_bfloat16* __restrict__ B2, const float* __restrict__ bias2,
                 const float* __restrict__ rrow,
                 __hip_bfloat16* __restrict__ out, int M) {
    constexpr int BKT = 32, LDKT = 40, K = CDIM, N = DFFN;
    __shared__ short As[128 * LDKT];
    __shared__ short Bs[64 * LDKT];
    __shared__ short Bs2[64 * LDKT];

    const int tid = threadIdx.x;
    const int m0 = blockIdx.x * 128;
    const int n0 = blockIdx.y * 64;
    const int wave = tid >> 6;
    const int lane = tid & 63;
    const int wm = (wave >> 1) * 64;
    const int wn = (wave & 1) * 32;
    const int fr = lane & 15;
    const int fq = lane >> 4;

    f32x4 acc[4][2] = {};
    f32x4 acc2[4][2] = {};

    // staging: A 512 chunks (2/thread), B1/B2 256 chunks (1/thread)
    const int arow = tid >> 2;            // 0..63 (+64 for second)
    const int akc = (tid & 3) * 8;
    const uint4 zero4 = make_uint4(0, 0, 0, 0);

    uint4 ra0, ra1, rb, rc;
    {
        const int gm0 = m0 + arow, gm1 = m0 + arow + 64;
        ra0 = (gm0 < M) ? *(const uint4*)&A[(size_t)gm0 * K + akc] : zero4;
        ra1 = (gm1 < M) ? *(const uint4*)&A[(size_t)gm1 * K + akc] : zero4;
        rb = *(const uint4*)&B1[(size_t)(n0 + arow) * K + akc];
        rc = *(const uint4*)&B2[(size_t)(n0 + arow) * K + akc];
    }

    for (int k0 = 0; k0 < K; k0 += BKT) {
        __syncthreads();
        {
            union { uint4 u; bf16x4 h[2]; } cv;
            short* pa0 = &As[arow * LDKT + akc];
            short* pa1 = &As[(arow + 64) * LDKT + akc];
            short* pb = &Bs[arow * LDKT + akc];
            short* pc = &Bs2[arow * LDKT + akc];
            cv.u = ra0; ((bf16x4*)pa0)[0] = cv.h[0]; ((bf16x4*)pa0)[1] = cv.h[1];
            cv.u = ra1; ((bf16x4*)pa1)[0] = cv.h[0]; ((bf16x4*)pa1)[1] = cv.h[1];
            cv.u = rb;  ((bf16x4*)pb)[0] = cv.h[0]; ((bf16x4*)pb)[1] = cv.h[1];
            cv.u = rc;  ((bf16x4*)pc)[0] = cv.h[0]; ((bf16x4*)pc)[1] = cv.h[1];
        }
        __syncthreads();

        if (k0 + BKT < K) {
            const int kn = k0 + BKT + akc;
            const int gm0 = m0 + arow, gm1 = m0 + arow + 64;
            ra0 = (gm0 < M) ? *(const uint4*)&A[(size_t)gm0 * K + kn] : zero4;
            ra1 = (gm1 < M) ? *(const uint4*)&A[(size_t)gm1 * K + kn] : zero4;
            rb = *(const uint4*)&B1[(size_t)(n0 + arow) * K + kn];
            rc = *(const uint4*)&B2[(size_t)(n0 + arow) * K + kn];
        }

        const int kq = fq * 8;
        bf16x8 af[4], bfr[2], bg[2];
#pragma unroll
        for (int i = 0; i < 4; ++i)
            af[i] = *(const bf16x8*)&As[(wm + i * 16 + fr) * LDKT + kq];
#pragma unroll
        for (int j = 0; j < 2; ++j) {
            bfr[j] = *(const bf16x8*)&Bs[(wn + j * 16 + fr) * LDKT + kq];
            bg[j] = *(const bf16x8*)&Bs2[(wn + j * 16 + fr) * LDKT + kq];
        }
#pragma unroll
        for (int i = 0; i < 4; ++i)
#pragma unroll
            for (int j = 0; j < 2; ++j) {
                acc[i][j] = __builtin_amdgcn_mfma_f32_16x16x32_bf16(af[i], bfr[j], acc[i][j], 0, 0, 0);
                acc2[i][j] = __builtin_amdgcn_mfma_f32_16x16x32_bf16(af[i], bg[j], acc2[i][j], 0, 0, 0);
            }
    }

#pragma unroll
    for (int i = 0; i < 4; ++i) {
#pragma unroll
        for (int r = 0; r < 4; ++r) {
            const int m = m0 + wm + i * 16 + fq * 4 + r;
            if (m >= M) continue;
            const float rm = rrow[m];
#pragma unroll
            for (int j = 0; j < 2; ++j) {
                const int n = n0 + wn + j * 16 + fr;
                const float v1 = acc[i][j][r] * rm + bias1[n];
                const float v2 = acc2[i][j][r] * rm + bias2[n];
                const float sig = 1.0f / (1.0f + expf(-v1));
                out[(size_t)m * N + n] = (__hip_bfloat16)(v1 * sig * v2);
            }
        }
    }
}

// ---------------------------------------------------------------------------
// MSDeformAttn sampling (v4): 4 tokens/block, fp8 value, bf16 proj.
// ---------------------------------------------------------------------------
__global__ __launch_bounds__(256)
void sample_kernel(const unsigned char* __restrict__ value,
                   const ushort* __restrict__ proj,
                   const float* __restrict__ ref,
                   __hip_bfloat16* __restrict__ out) {
    __shared__ float wsm[4][NHD][16];
    __shared__ int2  sTap[4][64][9];

    const int tok0 = blockIdx.x * 4;
    const int t = threadIdx.x;

    if (t < 32) {
        const int tl = t >> 3, h = t & 7;
        const int row = tok0 + tl;
        if (row < MTOK) {
            const ushort* lg = &proj[(size_t)row * 384 + 256 + h * 16];
            float v[16];
            float mx = -3.4e38f;
#pragma unroll
            for (int i = 0; i < 16; ++i) {
                v[i] = __uint_as_float((unsigned)lg[i] << 16);
                mx = fmaxf(mx, v[i]);
            }
            float s = 0.f;
#pragma unroll
            for (int i = 0; i < 16; ++i) { v[i] = expf(v[i] - mx); s += v[i]; }
            const float inv = 1.0f / s;
#pragma unroll
            for (int i = 0; i < 16; ++i) wsm[tl][h][i] = v[i] * inv;
        }
    }
    __syncthreads();

#pragma unroll
    for (int e = t; e < 512; e += 256) {
        const int tl = e >> 7, hp = e & 127;
        const int row = tok0 + tl;
        if (row < MTOK) {
            const int h = hp >> 4, pt = hp & 15, lv = pt >> 2;
            const int Hs[4] = {100, 50, 25, 13};
            const int Ws[4] = {134, 67, 34, 17};
            const int stt[4] = {0, 13400, 16750, 17600};
            const int H = Hs[lv], W = Ws[lv];
            const float rx = ref[((size_t)row * 4 + lv) * 2 + 0];
            const float ry = ref[((size_t)row * 4 + lv) * 2 + 1];
            const float ox = __uint_as_float((unsigned)proj[(size_t)row * 384 + h * 32 + pt * 2 + 0] << 16);
            const float oy = __uint_as_float((unsigned)proj[(size_t)row * 384 + h * 32 + pt * 2 + 1] << 16);
            const float xf = rx * (float)W + ox - 0.5f;
            const float yf = ry * (float)H + oy - 0.5f;
            const float x0f = floorf(xf), y0f = floorf(yf);
            const float fx = xf - x0f, fy = yf - y0f;
            const int x0 = (int)x0f, y0 = (int)y0f;
            const float aw = wsm[tl][h][pt];
            const int b = (row >= LQ) ? 1 : 0;
            const int base = (b * NHD + h) * LQ + stt[lv];
#pragma unroll
            for (int tap = 0; tap < 4; ++tap) {
                const int dy = tap >> 1, dx = tap & 1;
                const int xi = x0 + dx, yi = y0 + dy;
                const bool valid = (xi >= 0) & (xi < W) & (yi >= 0) & (yi < H);
                const float wgt = (dx ? fx : 1.f - fx) * (dy ? fy : 1.f - fy) * aw;
                sTap[tl][pt * 4 + tap][h] = valid
                    ? make_int2((base + yi * W + xi) * DHEAD, __float_as_int(wgt))
                    : make_int2(0, 0);
            }
        }
    }
    __syncthreads();

    const int tl = t >> 6, lane = t & 63;
    const int row = tok0 + tl;
    if (row >= MTOK) return;
    const int h = lane >> 3, c0 = (lane & 7) * 4;
    const unsigned char* vb = value + c0;
    float a0 = 0.f, a1 = 0.f, a2 = 0.f, a3 = 0.f;
#pragma unroll 8
    for (int i = 0; i < 64; ++i) {
        const int2 tp = sTap[tl][i][h];
        const float w = __int_as_float(tp.y);
        const unsigned d = *(const unsigned*)(vb + (size_t)tp.x);
        const f32x2 lo = fp8_dec2<false>(d);
        const f32x2 hi = fp8_dec2<true>(d);
        a0 = fmaf(w, lo[0], a0);
        a1 = fmaf(w, lo[1], a1);
        a2 = fmaf(w, hi[0], a2);
        a3 = fmaf(w, hi[1], a3);
    }
    ushort4 o;
    o.x = bfpack(a0); o.y = bfpack(a1); o.z = bfpack(a2); o.w = bfpack(a3);
    *(ushort4*)&out[(size_t)row * 256 + h * 32 + c0] = o;
}

// ---------------------------------------------------------------------------
// Workspace (bytes). MCb = 18.25 MB. Peak 7MCb + 2MB = 129.7 MB
// (R8 confirmed >= 148 MB available).
//   [0, MCb)              normed -> sampled
//   [MCb, 2MCb)           q -> x_bf
//   [2MCb, +9.1MB)        value fp8 -> (dead) r_f32 (142 KB)
//   [3MCb, +27.4MB)       proj bf16 -> (dead) overlapped by h
//   [3MCb, 7MCb)          h bf16 (73 MB), written after proj dead
//   [7MCb, +2MB)          bf16 weights
// ---------------------------------------------------------------------------
extern "C" void kernel_launch(void* const* d_in, const int* in_sizes, int n_in,
                              void* d_out, int out_size, void* d_ws, size_t ws_size,
                              hipStream_t stream) {
    const float* query      = (const float*)d_in[0];
    const float* query_pos  = (const float*)d_in[1];
    const float* ref        = (const float*)d_in[2];
    const float* norm_attn_w = (const float*)d_in[5];
    const float* Wv   = (const float*)d_in[6];
    const float* bv   = (const float*)d_in[7];
    const float* Woff = (const float*)d_in[8];
    const float* boff = (const float*)d_in[9];
    const float* Waw  = (const float*)d_in[10];
    const float* baw  = (const float*)d_in[11];
    const float* Wo   = (const float*)d_in[12];
    const float* bo   = (const float*)d_in[13];
    const float* ls_attn = (const float*)d_in[14];
    const float* norm_ffn_w = (const float*)d_in[15];
    const float* W1 = (const float*)d_in[16];
    const float* b1 = (const float*)d_in[17];
    const float* W2 = (const float*)d_in[18];
    const float* b2 = (const float*)d_in[19];
    const float* W3 = (const float*)d_in[20];
    const float* b3 = (const float*)d_in[21];
    const float* ls_ffn = (const float*)d_in[22];
    float* out = (float*)d_out;

    char* ws = (char*)d_ws;
    const size_t MCb = (size_t)MTOK * CDIM * 2;   // 18,248,704

    __hip_bfloat16* normed_bf  = (__hip_bfloat16*)(ws);
    __hip_bfloat16* q_bf       = (__hip_bfloat16*)(ws + MCb);
    unsigned char*  value_u8   = (unsigned char*)(ws + 2 * MCb);
    __hip_bfloat16* proj_bf    = (__hip_bfloat16*)(ws + 3 * MCb);
    __hip_bfloat16* sampled_bf = (__hip_bfloat16*)(ws);             // after normed/q dead
    __hip_bfloat16* x_bf       = (__hip_bfloat16*)(ws + MCb);       // after q dead
    float*          r_f        = (float*)(ws + 2 * MCb);            // after value dead
    __hip_bfloat16* h_bf       = (__hip_bfloat16*)(ws + 3 * MCb);   // after proj dead
    __hip_bfloat16* wbf        = (__hip_bfloat16*)(ws + 7 * MCb);

    __hip_bfloat16* Wv_bf    = wbf;
    __hip_bfloat16* Wproj_bf = wbf + 65536;    // Woff (256 rows) ++ Waw (128 rows)
    __hip_bfloat16* Wo_bf    = wbf + 163840;
    __hip_bfloat16* W1_bf    = wbf + 229376;   // norm_ffn_w folded
    __hip_bfloat16* W2_bf    = wbf + 491520;   // norm_ffn_w folded
    __hip_bfloat16* W3_bf    = wbf + 753664;

    // 0. all weight casts in one dispatch (W1/W2 get norm_ffn_w column-folded)
    CastJobs cj;
    cj.src[0] = Wv;   cj.dst[0] = Wv_bf;            cj.colw[0] = nullptr; cj.n[0] = 65536;
    cj.src[1] = Woff; cj.dst[1] = Wproj_bf;         cj.colw[1] = nullptr; cj.n[1] = 65536;
    cj.src[2] = Waw;  cj.dst[2] = Wproj_bf + 65536; cj.colw[2] = nullptr; cj.n[2] = 32768;
    cj.src[3] = Wo;   cj.dst[3] = Wo_bf;            cj.colw[3] = nullptr; cj.n[3] = 65536;
    cj.src[4] = W1;   cj.dst[4] = W1_bf;            cj.colw[4] = norm_ffn_w; cj.n[4] = 262144;
    cj.src[5] = W2;   cj.dst[5] = W2_bf;            cj.colw[5] = norm_ffn_w; cj.n[5] = 262144;
    cj.src[6] = W3;   cj.dst[6] = W3_bf;            cj.colw[6] = nullptr; cj.n[6] = 262144;
    cast_all<<<dim3(1024, 7), 256, 0, stream>>>(cj);

    const int gx = (MTOK + GBM - 1) / GBM;   // 279
    const int gr = (MTOK + 3) / 4;           // 8911

    // 1. normed_bf, q_bf = normed + pos
    rmsnorm_kernel<true><<<gr, 256, 0, stream>>>(query, query_pos, norm_attn_w, normed_bf, q_bf);
    // 2. value = normed @ Wv^T + bv -> fp8 (b,h,q,c)
    mfma_gemm<1, 64, unsigned char><<<dim3(gx, 2), 256, 0, stream>>>(
        normed_bf, Wv_bf, bv, nullptr, nullptr, nullptr, nullptr, value_u8, MTOK, CDIM, CDIM);
    // 3. proj = q @ [Woff;Waw]^T + [boff;baw] -> bf16 (M,384)
    mfma_gemm<4, 64, __hip_bfloat16><<<dim3(gx, 3), 256, 0, stream>>>(
        q_bf, Wproj_bf, boff, baw, nullptr, nullptr, nullptr, proj_bf, MTOK, 384, CDIM);
    // 4. deformable sampling -> sampled_bf
    sample_kernel<<<gr, 256, 0, stream>>>(value_u8, (const ushort*)proj_bf, ref, sampled_bf);
    // 5. x = query + ls_attn * (sampled @ Wo^T + bo) -> bf16
    mfma_gemm<2, 64, __hip_bfloat16><<<dim3(gx, 2), 256, 0, stream>>>(
        sampled_bf, Wo_bf, bo, nullptr, query, nullptr, ls_attn, x_bf, MTOK, CDIM, CDIM);
    // 6. r[m] = rsqrt(mean(x^2)+eps)
    rowrms_kernel<<<gr, 256, 0, stream>>>(x_bf, r_f);
    // 7. h = silu(r*(x@W1'^T)+b1) * (r*(x@W2'^T)+b2) -> bf16
    mfma_swiglu<<<dim3(gx, DFFN / 64), 256, 0, stream>>>(
        x_bf, W1_bf, b1, W2_bf, b2, r_f, h_bf, MTOK);
    // 8. out = x + ls_ffn * (h @ W3^T + b3) -> f32
    mfma_gemm<5, 64, float><<<dim3(gx, 2), 256, 0, stream>>>(
        h_bf, W3_bf, b3, nullptr, nullptr, x_bf, ls_ffn, out, MTOK, CDIM, DFFN);
}

// Round 10
// 385.443 us; speedup vs baseline: 4.7245x; 1.0566x over previous
//
#include <hip/hip_runtime.h>
#include <hip/hip_bf16.h>
#include <cstddef>

// Problem constants (static shapes from the reference)
#define LQ   17821
#define BS   2
#define MTOK (BS * LQ)       // 35642 token rows
#define CDIM 256
#define NHD  8
#define DHEAD 32
#define DFFN 1024

typedef short bf16x4 __attribute__((ext_vector_type(4)));
typedef short bf16x8 __attribute__((ext_vector_type(8)));
typedef float f32x4  __attribute__((ext_vector_type(4)));
typedef float f32x2  __attribute__((ext_vector_type(2)));

// ---------------------------------------------------------------------------
// fp8 e4m3 (OCP) encode/decode helpers — HW path with SW fallback
// ---------------------------------------------------------------------------
__device__ __forceinline__ unsigned char fp8_enc(float f) {
#if __has_builtin(__builtin_amdgcn_cvt_pk_fp8_f32)
    return (unsigned char)(__builtin_amdgcn_cvt_pk_fp8_f32(f, f, 0, false) & 0xff);
#else
    unsigned s = (__float_as_uint(f) >> 31) << 7;
    float af = fabsf(f);
    if (af < 0.0078125f) return (unsigned char)s;   // flush tiny/subnormal
    af = fminf(af, 448.f);
    unsigned b = __float_as_uint(af);
    int e = (int)(b >> 23) - 127 + 7;
    unsigned m = (b >> 20) & 7;
    if (b & 0x80000) { m++; if (m == 8) { m = 0; e++; } }
    if (e < 1) return (unsigned char)s;
    if (e > 15) { e = 15; m = 6; }
    return (unsigned char)(s | ((unsigned)e << 3) | m);
#endif
}

__device__ __forceinline__ float fp8_dec_byte(unsigned x) {
    unsigned s = (x >> 7) & 1, e = (x >> 3) & 15, m = x & 7;
    float v = e ? __uint_as_float(((e + 120u) << 23) | (m << 20))
                : (float)m * 0.001953125f;
    return s ? -v : v;
}

// Decode 2 fp8 bytes (low pair HI=false, high pair HI=true) of a dword.
template <bool HI>
__device__ __forceinline__ f32x2 fp8_dec2(unsigned d) {
#if __has_builtin(__builtin_amdgcn_cvt_pk_f32_fp8)
    return __builtin_amdgcn_cvt_pk_f32_fp8(d, HI);
#else
    f32x2 r;
    r[0] = fp8_dec_byte((d >> (HI ? 16 : 0)) & 0xff);
    r[1] = fp8_dec_byte((d >> (HI ? 24 : 8)) & 0xff);
    return r;
#endif
}

__device__ __forceinline__ ushort bfpack(float f) {
    __hip_bfloat16 h = (__hip_bfloat16)f;
    return *(ushort*)&h;
}

// Stage 8 fp8 bytes (uint2) -> 8 bf16 in LDS
__device__ __forceinline__ void stage_a8(short* p, uint2 d) {
    const f32x2 p0 = fp8_dec2<false>(d.x), p1 = fp8_dec2<true>(d.x);
    const f32x2 p2 = fp8_dec2<false>(d.y), p3 = fp8_dec2<true>(d.y);
    bf16x4 lo, hi;
    lo[0] = (short)bfpack(p0[0]); lo[1] = (short)bfpack(p0[1]);
    lo[2] = (short)bfpack(p1[0]); lo[3] = (short)bfpack(p1[1]);
    hi[0] = (short)bfpack(p2[0]); hi[1] = (short)bfpack(p2[1]);
    hi[2] = (short)bfpack(p3[0]); hi[3] = (short)bfpack(p3[1]);
    ((bf16x4*)p)[0] = lo;
    ((bf16x4*)p)[1] = hi;
}

// ---------------------------------------------------------------------------
// Batched fp32 -> bf16 weight cast; optional per-column scale (norm folding)
// ---------------------------------------------------------------------------
struct CastJobs {
    const float* src[7];
    __hip_bfloat16* dst[7];
    const float* colw[7];   // if non-null: dst = src * colw[i & 255]
    int n[7];
};

__global__ __launch_bounds__(256)
void cast_all(CastJobs j) {
    const int seg = blockIdx.y;
    const int i = blockIdx.x * 256 + threadIdx.x;
    if (i < j.n[seg]) {
        float v = j.src[seg][i];
        if (j.colw[seg]) v *= j.colw[seg][i & 255];
        j.dst[seg][i] = (__hip_bfloat16)v;
    }
}

// ---------------------------------------------------------------------------
// RMSNorm, wave-per-token (64 lanes x float4 = 256 ch), 4 tokens/block.
// ---------------------------------------------------------------------------
template <bool ADD_POS>
__global__ __launch_bounds__(256)
void rmsnorm_kernel(const float* __restrict__ x, const float* __restrict__ pos,
                    const float* __restrict__ w,
                    __hip_bfloat16* __restrict__ outN, __hip_bfloat16* __restrict__ outQ) {
    const int tok = blockIdx.x * 4 + (threadIdx.x >> 6);
    if (tok >= MTOK) return;
    const int lane = threadIdx.x & 63;
    const size_t base = (size_t)tok * CDIM + lane * 4;
    const float4 v = *(const float4*)&x[base];
    float ss = v.x * v.x + v.y * v.y + v.z * v.z + v.w * v.w;
#pragma unroll
    for (int m = 1; m < 64; m <<= 1) ss += __shfl_xor(ss, m, 64);
    const float r = rsqrtf(ss * (1.0f / CDIM) + 1e-6f);
    const float4 wv = *(const float4*)&w[lane * 4];
    const float n0 = v.x * r * wv.x, n1 = v.y * r * wv.y;
    const float n2 = v.z * r * wv.z, n3 = v.w * r * wv.w;
    ushort4 o;
    o.x = bfpack(n0); o.y = bfpack(n1); o.z = bfpack(n2); o.w = bfpack(n3);
    *(ushort4*)&outN[base] = o;
    if (ADD_POS) {
        const float4 p = *(const float4*)&pos[base];
        ushort4 q;
        q.x = bfpack(n0 + p.x); q.y = bfpack(n1 + p.y);
        q.z = bfpack(n2 + p.z); q.w = bfpack(n3 + p.w);
        *(ushort4*)&outQ[base] = q;
    }
}

// ---------------------------------------------------------------------------
// Row RMS scale only: r[m] = rsqrt(mean(x^2)+eps), x bf16. 4 tokens/block.
// ---------------------------------------------------------------------------
__global__ __launch_bounds__(256)
void rowrms_kernel(const __hip_bfloat16* __restrict__ x, float* __restrict__ r) {
    const int tok = blockIdx.x * 4 + (threadIdx.x >> 6);
    if (tok >= MTOK) return;
    const int lane = threadIdx.x & 63;
    const ushort4 u = *(const ushort4*)&x[(size_t)tok * CDIM + lane * 4];
    const float v0 = __uint_as_float((unsigned)u.x << 16);
    const float v1 = __uint_as_float((unsigned)u.y << 16);
    const float v2 = __uint_as_float((unsigned)u.z << 16);
    const float v3 = __uint_as_float((unsigned)u.w << 16);
    float ss = v0 * v0 + v1 * v1 + v2 * v2 + v3 * v3;
#pragma unroll
    for (int m = 1; m < 64; m <<= 1) ss += __shfl_xor(ss, m, 64);
    if (lane == 0) r[tok] = rsqrtf(ss * (1.0f / CDIM) + 1e-6f);
}

// ---------------------------------------------------------------------------
// bf16 MFMA GEMM: C[M,N] = A[M,K] @ W[N,K]^T (+ epilogues), fp32 accumulate.
// 128x128 block tile, templated BK, 4 waves (2x2), wave = 4x4 of 16x16x32.
// Flat grid, n-fastest swizzle: m0 = bid/nsw, n0 = bid%nsw (L2 A-reuse).
// A8: A operand stored fp8 e4m3, decoded to bf16 during LDS staging.
// MODE 0: out = acc + bias1
// MODE 1: value layout write (b, h, q, c), fp8 e4m3
// MODE 2: out = resid_f32 + ls * (acc + bias1)
// MODE 4: out = acc + concat(bias1[0:256], bias2[0:128])[n]   (proj N=384)
// MODE 5: out = resid_bf16 + ls * (acc + bias1), f32 out
// ---------------------------------------------------------------------------
#define GBM 128
#define GBN 128

template <int MODE, int BKT, typename OUTT, bool A8 = false>
__global__ __launch_bounds__(256, 2)
void mfma_gemm(const void* __restrict__ Av,
               const __hip_bfloat16* __restrict__ B1, const float* __restrict__ bias1,
               const float* __restrict__ bias2,
               const float* __restrict__ resid, const __hip_bfloat16* __restrict__ residb,
               const float* __restrict__ ls,
               OUTT* __restrict__ out, int M, int N, int K, int nsw) {
    constexpr int LDKT = BKT + 8;        // +16B pad: 2-way bank alias (free)
    constexpr int CH = BKT / 16;         // staging chunks per thread per matrix
    constexpr int CPR = BKT / 8;         // 8-elem chunks per row

    __shared__ short As[GBM * LDKT];
    __shared__ short Bs[GBN * LDKT];

    const __hip_bfloat16* A = (const __hip_bfloat16*)Av;
    const unsigned char* A8p = (const unsigned char*)Av;

    const int tid = threadIdx.x;
    const int bid = blockIdx.x;
    const int m0 = (bid / nsw) * GBM;
    const int n0 = (bid % nsw) * GBN;
    const int wave = tid >> 6;
    const int lane = tid & 63;
    const int wm = (wave >> 1) * 64;
    const int wn = (wave & 1) * 64;
    const int fr = lane & 15;   // col of C
    const int fq = lane >> 4;   // quad: k = fq*8+j ; C row = fq*4+r

    f32x4 acc[4][4] = {};

    int srow[CH], skc[CH];
#pragma unroll
    for (int cc = 0; cc < CH; ++cc) {
        const int g = tid + cc * 256;
        srow[cc] = g / CPR;
        skc[cc] = (g % CPR) * 8;
    }
    const uint4 zero4 = make_uint4(0, 0, 0, 0);
    const uint2 zero2 = make_uint2(0, 0);

    uint4 ra[CH], rb[CH];
    uint2 ra8[A8 ? CH : 1];
#pragma unroll
    for (int cc = 0; cc < CH; ++cc) {
        const int gm = m0 + srow[cc];
        if constexpr (A8)
            ra8[cc] = (gm < M) ? *(const uint2*)&A8p[(size_t)gm * K + skc[cc]] : zero2;
        else
            ra[cc] = (gm < M) ? *(const uint4*)&A[(size_t)gm * K + skc[cc]] : zero4;
        rb[cc] = *(const uint4*)&B1[(size_t)(n0 + srow[cc]) * K + skc[cc]];
    }

    for (int k0 = 0; k0 < K; k0 += BKT) {
        __syncthreads();
#pragma unroll
        for (int cc = 0; cc < CH; ++cc) {
            short* pa = &As[srow[cc] * LDKT + skc[cc]];
            short* pb = &Bs[srow[cc] * LDKT + skc[cc]];
            if constexpr (A8) {
                stage_a8(pa, ra8[cc]);
            } else {
                union { uint4 u; bf16x4 h[2]; } cv;
                cv.u = ra[cc]; ((bf16x4*)pa)[0] = cv.h[0]; ((bf16x4*)pa)[1] = cv.h[1];
            }
            union { uint4 u; bf16x4 h[2]; } cv;
            cv.u = rb[cc]; ((bf16x4*)pb)[0] = cv.h[0]; ((bf16x4*)pb)[1] = cv.h[1];
        }
        __syncthreads();

        if (k0 + BKT < K) {
            const int kn = k0 + BKT;
#pragma unroll
            for (int cc = 0; cc < CH; ++cc) {
                const int gm = m0 + srow[cc];
                if constexpr (A8)
                    ra8[cc] = (gm < M) ? *(const uint2*)&A8p[(size_t)gm * K + kn + skc[cc]] : zero2;
                else
                    ra[cc] = (gm < M) ? *(const uint4*)&A[(size_t)gm * K + kn + skc[cc]] : zero4;
                rb[cc] = *(const uint4*)&B1[(size_t)(n0 + srow[cc]) * K + kn + skc[cc]];
            }
        }

#pragma unroll
        for (int kk = 0; kk < BKT; kk += 32) {
            const int kq = kk + fq * 8;
            bf16x8 af[4], bfr[4];
#pragma unroll
            for (int i = 0; i < 4; ++i)
                af[i] = *(const bf16x8*)&As[(wm + i * 16 + fr) * LDKT + kq];
#pragma unroll
            for (int j = 0; j < 4; ++j)
                bfr[j] = *(const bf16x8*)&Bs[(wn + j * 16 + fr) * LDKT + kq];
#pragma unroll
            for (int i = 0; i < 4; ++i)
#pragma unroll
                for (int j = 0; j < 4; ++j)
                    acc[i][j] = __builtin_amdgcn_mfma_f32_16x16x32_bf16(af[i], bfr[j], acc[i][j], 0, 0, 0);
        }
    }

#pragma unroll
    for (int i = 0; i < 4; ++i) {
#pragma unroll
        for (int r = 0; r < 4; ++r) {
            const int m = m0 + wm + i * 16 + fq * 4 + r;
            if (m >= M) continue;
#pragma unroll
            for (int j = 0; j < 4; ++j) {
                const int n = n0 + wn + j * 16 + fr;
                float v;
                if constexpr (MODE == 4)
                    v = acc[i][j][r] + ((n < 256) ? bias1[n] : bias2[n - 256]);
                else
                    v = acc[i][j][r] + bias1[n];
                if constexpr (MODE == 0 || MODE == 4) {
                    out[(size_t)m * N + n] = (OUTT)v;
                } else if constexpr (MODE == 1) {
                    const int b = (m >= LQ) ? 1 : 0;
                    const int qi = m - b * LQ;
                    const int h = n >> 5;
                    const int c = n & 31;
                    ((unsigned char*)out)[((size_t)(b * NHD + h) * LQ + qi) * DHEAD + c] = fp8_enc(v);
                } else if constexpr (MODE == 2) {
                    out[(size_t)m * N + n] =
                        (OUTT)(resid[(size_t)m * N + n] + ls[n] * v);
                } else {  // MODE 5: bf16 residual, f32 out
                    const float rx = __uint_as_float(
                        (unsigned)(*(const ushort*)&residb[(size_t)m * N + n]) << 16);
                    out[(size_t)m * N + n] = (OUTT)(rx + ls[n] * v);
                }
            }
        }
    }
}

// ---------------------------------------------------------------------------
// SwiGLU dual GEMM: h = silu(r[m]*(x@W1'^T)+b1) * (r[m]*(x@W2'^T)+b2)
// 128x64 block tile, BK=32, 4 waves 2x2, wave 64x32 per matrix.
// Flat grid, n-fastest swizzle (16 n-tiles). h written fp8 e4m3.
// ---------------------------------------------------------------------------
__global__ __launch_bounds__(256, 3)
void mfma_swiglu(const __hip_bfloat16* __restrict__ A,
                 const __hip_bfloat16* __restrict__ B1, const float* __restrict__ bias1,
                 const __hip_bfloat16* __restrict__ B2, const float* __restrict__ bias2,
                 const float* __restrict__ rrow,
                 unsigned char* __restrict__ out, int M) {
    constexpr int BKT = 32, LDKT = 40, K = CDIM, N = DFFN;
    __shared__ short As[128 * LDKT];
    __shared__ short Bs[64 * LDKT];
    __shared__ short Bs2[64 * LDKT];

    const int tid = threadIdx.x;
    const int bid = blockIdx.x;
    const int m0 = (bid >> 4) * 128;     // n-fastest: 16 consecutive blocks share A
    const int n0 = (bid & 15) * 64;
    const int wave = tid >> 6;
    const int lane = tid & 63;
    const int wm = (wave >> 1) * 64;
    const int wn = (wave & 1) * 32;
    const int fr = lane & 15;
    const int fq = lane >> 4;

    f32x4 acc[4][2] = {};
    f32x4 acc2[4][2] = {};

    const int arow = tid >> 2;            // 0..63 (+64 for second)
    const int akc = (tid & 3) * 8;
    const uint4 zero4 = make_uint4(0, 0, 0, 0);

    uint4 ra0, ra1, rb, rc;
    {
        const int gm0 = m0 + arow, gm1 = m0 + arow + 64;
        ra0 = (gm0 < M) ? *(const uint4*)&A[(size_t)gm0 * K + akc] : zero4;
        ra1 = (gm1 < M) ? *(const uint4*)&A[(size_t)gm1 * K + akc] : zero4;
        rb = *(const uint4*)&B1[(size_t)(n0 + arow) * K + akc];
        rc = *(const uint4*)&B2[(size_t)(n0 + arow) * K + akc];
    }

    for (int k0 = 0; k0 < K; k0 += BKT) {
        __syncthreads();
        {
            union { uint4 u; bf16x4 h[2]; } cv;
            short* pa0 = &As[arow * LDKT + akc];
            short* pa1 = &As[(arow + 64) * LDKT + akc];
            short* pb = &Bs[arow * LDKT + akc];
            short* pc = &Bs2[arow * LDKT + akc];
            cv.u = ra0; ((bf16x4*)pa0)[0] = cv.h[0]; ((bf16x4*)pa0)[1] = cv.h[1];
            cv.u = ra1; ((bf16x4*)pa1)[0] = cv.h[0]; ((bf16x4*)pa1)[1] = cv.h[1];
            cv.u = rb;  ((bf16x4*)pb)[0] = cv.h[0]; ((bf16x4*)pb)[1] = cv.h[1];
            cv.u = rc;  ((bf16x4*)pc)[0] = cv.h[0]; ((bf16x4*)pc)[1] = cv.h[1];
        }
        __syncthreads();

        if (k0 + BKT < K) {
            const int kn = k0 + BKT + akc;
            const int gm0 = m0 + arow, gm1 = m0 + arow + 64;
            ra0 = (gm0 < M) ? *(const uint4*)&A[(size_t)gm0 * K + kn] : zero4;
            ra1 = (gm1 < M) ? *(const uint4*)&A[(size_t)gm1 * K + kn] : zero4;
            rb = *(const uint4*)&B1[(size_t)(n0 + arow) * K + kn];
            rc = *(const uint4*)&B2[(size_t)(n0 + arow) * K + kn];
        }

        const int kq = fq * 8;
        bf16x8 af[4], bfr[2], bg[2];
#pragma unroll
        for (int i = 0; i < 4; ++i)
            af[i] = *(const bf16x8*)&As[(wm + i * 16 + fr) * LDKT + kq];
#pragma unroll
        for (int j = 0; j < 2; ++j) {
            bfr[j] = *(const bf16x8*)&Bs[(wn + j * 16 + fr) * LDKT + kq];
            bg[j] = *(const bf16x8*)&Bs2[(wn + j * 16 + fr) * LDKT + kq];
        }
#pragma unroll
        for (int i = 0; i < 4; ++i)
#pragma unroll
            for (int j = 0; j < 2; ++j) {
                acc[i][j] = __builtin_amdgcn_mfma_f32_16x16x32_bf16(af[i], bfr[j], acc[i][j], 0, 0, 0);
                acc2[i][j] = __builtin_amdgcn_mfma_f32_16x16x32_bf16(af[i], bg[j], acc2[i][j], 0, 0, 0);
            }
    }

#pragma unroll
    for (int i = 0; i < 4; ++i) {
#pragma unroll
        for (int r = 0; r < 4; ++r) {
            const int m = m0 + wm + i * 16 + fq * 4 + r;
            if (m >= M) continue;
            const float rm = rrow[m];
#pragma unroll
            for (int j = 0; j < 2; ++j) {
                const int n = n0 + wn + j * 16 + fr;
                const float v1 = acc[i][j][r] * rm + bias1[n];
                const float v2 = acc2[i][j][r] * rm + bias2[n];
                const float sig = 1.0f / (1.0f + expf(-v1));
                out[(size_t)m * N + n] = fp8_enc(v1 * sig * v2);
            }
        }
    }
}

// ---------------------------------------------------------------------------
// MSDeformAttn sampling (v4): 4 tokens/block, fp8 value, bf16 proj.
// ---------------------------------------------------------------------------
__global__ __launch_bounds__(256)
void sample_kernel(const unsigned char* __restrict__ value,
                   const ushort* __restrict__ proj,
                   const float* __restrict__ ref,
                   __hip_bfloat16* __restrict__ out) {
    __shared__ float wsm[4][NHD][16];
    __shared__ int2  sTap[4][64][9];

    const int tok0 = blockIdx.x * 4;
    const int t = threadIdx.x;

    if (t < 32) {
        const int tl = t >> 3, h = t & 7;
        const int row = tok0 + tl;
        if (row < MTOK) {
            const ushort* lg = &proj[(size_t)row * 384 + 256 + h * 16];
            float v[16];
            float mx = -3.4e38f;
#pragma unroll
            for (int i = 0; i < 16; ++i) {
                v[i] = __uint_as_float((unsigned)lg[i] << 16);
                mx = fmaxf(mx, v[i]);
            }
            float s = 0.f;
#pragma unroll
            for (int i = 0; i < 16; ++i) { v[i] = expf(v[i] - mx); s += v[i]; }
            const float inv = 1.0f / s;
#pragma unroll
            for (int i = 0; i < 16; ++i) wsm[tl][h][i] = v[i] * inv;
        }
    }
    __syncthreads();

#pragma unroll
    for (int e = t; e < 512; e += 256) {
        const int tl = e >> 7, hp = e & 127;
        const int row = tok0 + tl;
        if (row < MTOK) {
            const int h = hp >> 4, pt = hp & 15, lv = pt >> 2;
            const int Hs[4] = {100, 50, 25, 13};
            const int Ws[4] = {134, 67, 34, 17};
            const int stt[4] = {0, 13400, 16750, 17600};
            const int H = Hs[lv], W = Ws[lv];
            const float rx = ref[((size_t)row * 4 + lv) * 2 + 0];
            const float ry = ref[((size_t)row * 4 + lv) * 2 + 1];
            const float ox = __uint_as_float((unsigned)proj[(size_t)row * 384 + h * 32 + pt * 2 + 0] << 16);
            const float oy = __uint_as_float((unsigned)proj[(size_t)row * 384 + h * 32 + pt * 2 + 1] << 16);
            const float xf = rx * (float)W + ox - 0.5f;
            const float yf = ry * (float)H + oy - 0.5f;
            const float x0f = floorf(xf), y0f = floorf(yf);
            const float fx = xf - x0f, fy = yf - y0f;
            const int x0 = (int)x0f, y0 = (int)y0f;
            const float aw = wsm[tl][h][pt];
            const int b = (row >= LQ) ? 1 : 0;
            const int base = (b * NHD + h) * LQ + stt[lv];
#pragma unroll
            for (int tap = 0; tap < 4; ++tap) {
                const int dy = tap >> 1, dx = tap & 1;
                const int xi = x0 + dx, yi = y0 + dy;
                const bool valid = (xi >= 0) & (xi < W) & (yi >= 0) & (yi < H);
                const float wgt = (dx ? fx : 1.f - fx) * (dy ? fy : 1.f - fy) * aw;
                sTap[tl][pt * 4 + tap][h] = valid
                    ? make_int2((base + yi * W + xi) * DHEAD, __float_as_int(wgt))
                    : make_int2(0, 0);
            }
        }
    }
    __syncthreads();

    const int tl = t >> 6, lane = t & 63;
    const int row = tok0 + tl;
    if (row >= MTOK) return;
    const int h = lane >> 3, c0 = (lane & 7) * 4;
    const unsigned char* vb = value + c0;
    float a0 = 0.f, a1 = 0.f, a2 = 0.f, a3 = 0.f;
#pragma unroll 8
    for (int i = 0; i < 64; ++i) {
        const int2 tp = sTap[tl][i][h];
        const float w = __int_as_float(tp.y);
        const unsigned d = *(const unsigned*)(vb + (size_t)tp.x);
        const f32x2 lo = fp8_dec2<false>(d);
        const f32x2 hi = fp8_dec2<true>(d);
        a0 = fmaf(w, lo[0], a0);
        a1 = fmaf(w, lo[1], a1);
        a2 = fmaf(w, hi[0], a2);
        a3 = fmaf(w, hi[1], a3);
    }
    ushort4 o;
    o.x = bfpack(a0); o.y = bfpack(a1); o.z = bfpack(a2); o.w = bfpack(a3);
    *(ushort4*)&out[(size_t)row * 256 + h * 32 + c0] = o;
}

// ---------------------------------------------------------------------------
// Workspace (bytes). MCb = 18.25 MB. Peak 7MCb + 2MB = 129.7 MB.
//   [0, MCb)              normed -> sampled
//   [MCb, 2MCb)           q -> x_bf
//   [2MCb, +9.1MB)        value fp8 -> (dead) r_f32 (142 KB)
//   [3MCb, +27.4MB)       proj bf16 -> (dead) h fp8 (36.5 MB) after sampling
//   [7MCb, +2MB)          bf16 weights
// ---------------------------------------------------------------------------
extern "C" void kernel_launch(void* const* d_in, const int* in_sizes, int n_in,
                              void* d_out, int out_size, void* d_ws, size_t ws_size,
                              hipStream_t stream) {
    const float* query      = (const float*)d_in[0];
    const float* query_pos  = (const float*)d_in[1];
    const float* ref        = (const float*)d_in[2];
    const float* norm_attn_w = (const float*)d_in[5];
    const float* Wv   = (const float*)d_in[6];
    const float* bv   = (const float*)d_in[7];
    const float* Woff = (const float*)d_in[8];
    const float* boff = (const float*)d_in[9];
    const float* Waw  = (const float*)d_in[10];
    const float* baw  = (const float*)d_in[11];
    const float* Wo   = (const float*)d_in[12];
    const float* bo   = (const float*)d_in[13];
    const float* ls_attn = (const float*)d_in[14];
    const float* norm_ffn_w = (const float*)d_in[15];
    const float* W1 = (const float*)d_in[16];
    const float* b1 = (const float*)d_in[17];
    const float* W2 = (const float*)d_in[18];
    const float* b2 = (const float*)d_in[19];
    const float* W3 = (const float*)d_in[20];
    const float* b3 = (const float*)d_in[21];
    const float* ls_ffn = (const float*)d_in[22];
    float* out = (float*)d_out;

    char* ws = (char*)d_ws;
    const size_t MCb = (size_t)MTOK * CDIM * 2;   // 18,248,704

    __hip_bfloat16* normed_bf  = (__hip_bfloat16*)(ws);
    __hip_bfloat16* q_bf       = (__hip_bfloat16*)(ws + MCb);
    unsigned char*  value_u8   = (unsigned char*)(ws + 2 * MCb);
    __hip_bfloat16* proj_bf    = (__hip_bfloat16*)(ws + 3 * MCb);
    __hip_bfloat16* sampled_bf = (__hip_bfloat16*)(ws);             // after normed/q dead
    __hip_bfloat16* x_bf       = (__hip_bfloat16*)(ws + MCb);       // after q dead
    float*          r_f        = (float*)(ws + 2 * MCb);            // after value dead
    unsigned char*  h_u8       = (unsigned char*)(ws + 3 * MCb);    // after proj dead
    __hip_bfloat16* wbf        = (__hip_bfloat16*)(ws + 7 * MCb);

    __hip_bfloat16* Wv_bf    = wbf;
    __hip_bfloat16* Wproj_bf = wbf + 65536;    // Woff (256 rows) ++ Waw (128 rows)
    __hip_bfloat16* Wo_bf    = wbf + 163840;
    __hip_bfloat16* W1_bf    = wbf + 229376;   // norm_ffn_w folded
    __hip_bfloat16* W2_bf    = wbf + 491520;   // norm_ffn_w folded
    __hip_bfloat16* W3_bf    = wbf + 753664;

    // 0. all weight casts in one dispatch (W1/W2 get norm_ffn_w column-folded)
    CastJobs cj;
    cj.src[0] = Wv;   cj.dst[0] = Wv_bf;            cj.colw[0] = nullptr; cj.n[0] = 65536;
    cj.src[1] = Woff; cj.dst[1] = Wproj_bf;         cj.colw[1] = nullptr; cj.n[1] = 65536;
    cj.src[2] = Waw;  cj.dst[2] = Wproj_bf + 65536; cj.colw[2] = nullptr; cj.n[2] = 32768;
    cj.src[3] = Wo;   cj.dst[3] = Wo_bf;            cj.colw[3] = nullptr; cj.n[3] = 65536;
    cj.src[4] = W1;   cj.dst[4] = W1_bf;            cj.colw[4] = norm_ffn_w; cj.n[4] = 262144;
    cj.src[5] = W2;   cj.dst[5] = W2_bf;            cj.colw[5] = norm_ffn_w; cj.n[5] = 262144;
    cj.src[6] = W3;   cj.dst[6] = W3_bf;            cj.colw[6] = nullptr; cj.n[6] = 262144;
    cast_all<<<dim3(1024, 7), 256, 0, stream>>>(cj);

    const int gx = (MTOK + GBM - 1) / GBM;   // 279
    const int gr = (MTOK + 3) / 4;           // 8911

    // 1. normed_bf, q_bf = normed + pos
    rmsnorm_kernel<true><<<gr, 256, 0, stream>>>(query, query_pos, norm_attn_w, normed_bf, q_bf);
    // 2. value = normed @ Wv^T + bv -> fp8 (b,h,q,c)
    mfma_gemm<1, 64, unsigned char><<<gx * 2, 256, 0, stream>>>(
        normed_bf, Wv_bf, bv, nullptr, nullptr, nullptr, nullptr, value_u8, MTOK, CDIM, CDIM, 2);
    // 3. proj = q @ [Woff;Waw]^T + [boff;baw] -> bf16 (M,384)
    mfma_gemm<4, 64, __hip_bfloat16><<<gx * 3, 256, 0, stream>>>(
        q_bf, Wproj_bf, boff, baw, nullptr, nullptr, nullptr, proj_bf, MTOK, 384, CDIM, 3);
    // 4. deformable sampling -> sampled_bf
    sample_kernel<<<gr, 256, 0, stream>>>(value_u8, (const ushort*)proj_bf, ref, sampled_bf);
    // 5. x = query + ls_attn * (sampled @ Wo^T + bo) -> bf16
    mfma_gemm<2, 64, __hip_bfloat16><<<gx * 2, 256, 0, stream>>>(
        sampled_bf, Wo_bf, bo, nullptr, query, nullptr, ls_attn, x_bf, MTOK, CDIM, CDIM, 2);
    // 6. r[m] = rsqrt(mean(x^2)+eps)
    rowrms_kernel<<<gr, 256, 0, stream>>>(x_bf, r_f);
    // 7. h = silu(r*(x@W1'^T)+b1) * (r*(x@W2'^T)+b2) -> fp8
    mfma_swiglu<<<gx * 16, 256, 0, stream>>>(
        x_bf, W1_bf, b1, W2_bf, b2, r_f, h_u8, MTOK);
    // 8. out = x + ls_ffn * (h @ W3^T + b3) -> f32 (A is fp8)
    mfma_gemm<5, 64, float, true><<<gx * 2, 256, 0, stream>>>(
        h_u8, W3_bf, b3, nullptr, nullptr, x_bf, ls_ffn, out, MTOK, CDIM, DFFN, 2);
}